// Round 15
// baseline (787.120 us; speedup 1.0000x reference)
//
#include <hip/hip_runtime.h>
#include <hip/hip_bf16.h>
#include <math.h>

#define N_Gc 50000
#define N_Dc 50000
#define DIM 64
#define RNK 32
#define NNZc 1600000
#define BSZ 2048
#define KEEPV (1.0f/0.9f)
#define INVT 5.0f
#define NBK3 391     // (50000+127)/128 buckets of 128 rows
#define NBLK 200     // NNZ/EPB scatter blocks
#define NSL 48       // j-slices for lse grid
#define EPB 8000     // edges per block (hist3 + phaseA)
#define MCH 256      // matred i-chunk per block
#define MBLK 196     // ceil(50000/256)
#define SCAP 6144    // LDS sort capacity (records) in phaseB3

typedef __attribute__((ext_vector_type(8))) short bfrag;
typedef __attribute__((ext_vector_type(4))) float f32x4;
typedef unsigned long long u64;
typedef unsigned int u32;

__device__ inline ushort f2bf(float f) {
  union { float f; unsigned int u; } v; v.f = f;
  unsigned int r = (v.u + 0x7fffu + ((v.u >> 16) & 1u)) >> 16;
  return (ushort)r;
}
__device__ inline float bf2f(u32 u) {
  union { unsigned int i; float f; } v; v.i = u << 16;
  return v.f;
}

// ---------------- hist3: per-(bucket,block) dense counts, no global atomics ----------------
__global__ __launch_bounds__(256) void hist3_kernel(const int* __restrict__ rows, const int* __restrict__ cols,
                                                    int* __restrict__ cntR, int* __restrict__ cntC) {
  __shared__ int lh_r[NBK3];
  __shared__ int lh_c[NBK3];
  int t = threadIdx.x, blk = blockIdx.x;
  for (int j = t; j < NBK3; j += 256) { lh_r[j] = 0; lh_c[j] = 0; }
  __syncthreads();
  int e0 = blk*EPB;
  for (int i = e0 + t; i < e0 + EPB; i += 256) {
    atomicAdd(&lh_r[__builtin_nontemporal_load(&rows[i]) >> 7], 1);
    atomicAdd(&lh_c[__builtin_nontemporal_load(&cols[i]) >> 7], 1);
  }
  __syncthreads();
  for (int j = t; j < NBK3; j += 256) {
    cntR[j*NBLK + blk] = lh_r[j];
    cntC[j*NBLK + blk] = lh_c[j];
  }
}

// ---------------- cscan2: prefix over [bucket][block] counts -> per-block bases + bucket ptr ----------------
__global__ __launch_bounds__(1024) void cscan2_kernel(const int* __restrict__ cntA, int* __restrict__ cbA, int* __restrict__ bpA,
                                                      const int* __restrict__ cntB, int* __restrict__ cbB, int* __restrict__ bpB) {
  const int n = NBK3*NBLK;
  const int* cnt = blockIdx.x ? cntB : cntA;
  int* cb = blockIdx.x ? cbB : cbA;
  int* bp = blockIdx.x ? bpB : bpA;
  __shared__ int wsum[16];
  int t = threadIdx.x, lane = t & 63, w = t >> 6;
  int carry = 0;
  for (int base = 0; base < n; base += 1024) {
    int i = base + t;
    int v = (i < n) ? cnt[i] : 0;
    int x = v;
    #pragma unroll
    for (int o = 1; o < 64; o <<= 1) { int y = __shfl_up(x, o); if (lane >= o) x += y; }
    if (lane == 63) wsum[w] = x;
    __syncthreads();
    if (t < 16) {
      int s = wsum[t];
      #pragma unroll
      for (int o = 1; o < 16; o <<= 1) { int y = __shfl_up(s, o); if (t >= o) s += y; }
      wsum[t] = s;
    }
    __syncthreads();
    int wpre = (w == 0) ? 0 : wsum[w-1];
    int total = wsum[15];
    int ex = carry + wpre + (x - v);
    if (i < n) {
      cb[i] = ex;
      if (i % NBLK == 0) bp[i/NBLK] = ex;
    }
    carry += total;
    __syncthreads();
  }
  if (t == 0) bp[NBK3] = carry;
}

// ---------------- phase A: single-pass deterministic scatter (no global atomics) ----------------
// record u64: lo32 = other_id[0:15] | rel[16:23] | d0<<24 | d1<<25 ; hi32 = val bits
__global__ __launch_bounds__(256) void phaseA2_kernel(const int* __restrict__ rows, const int* __restrict__ cols,
    const float* __restrict__ vals, const float* __restrict__ drop,
    const int* __restrict__ cbR, const int* __restrict__ cbC,
    u64* __restrict__ stage_r, u64* __restrict__ stage_c) {
  __shared__ int cnt_r[NBK3], cnt_c[NBK3];
  __shared__ int base_r[NBK3], base_c[NBK3];
  int t = threadIdx.x, blk = blockIdx.x;
  for (int j = t; j < NBK3; j += 256) {
    cnt_r[j] = 0; cnt_c[j] = 0;
    base_r[j] = cbR[j*NBLK + blk];
    base_c[j] = cbC[j*NBLK + blk];
  }
  __syncthreads();
  int e0 = blk*EPB;
  for (int i = e0 + t; i < e0 + EPB; i += 256) {
    int r = __builtin_nontemporal_load(&rows[i]);
    int c = __builtin_nontemporal_load(&cols[i]);
    u64 vb = (u64)__float_as_uint(__builtin_nontemporal_load(&vals[i])) << 32;
    unsigned int dr0 = (__builtin_nontemporal_load(&drop[i]) > 0.1f) ? (1u<<24) : 0u;
    unsigned int dc0 = (__builtin_nontemporal_load(&drop[(size_t)NNZc + i]) > 0.1f) ? (1u<<24) : 0u;
    unsigned int dr1 = (__builtin_nontemporal_load(&drop[2*(size_t)NNZc + i]) > 0.1f) ? (1u<<25) : 0u;
    unsigned int dc1 = (__builtin_nontemporal_load(&drop[3*(size_t)NNZc + i]) > 0.1f) ? (1u<<25) : 0u;
    int br = r >> 7, bc = c >> 7;
    int p = base_r[br] + atomicAdd(&cnt_r[br], 1);
    stage_r[p] = vb | (unsigned int)c | ((unsigned int)(r & 127) << 16) | dr0 | dr1;
    int q = base_c[bc] + atomicAdd(&cnt_c[bc], 1);
    stage_c[q] = vb | (unsigned int)r | ((unsigned int)(c & 127) << 16) | dc0 | dc1;
  }
}

// ---------------- phase B3 (merged sides): LDS sort (row-grouped, col-ascending), sequential writeout ----------------
// ew: col[0:15] | bf16(weight)[16:31]
__global__ __launch_bounds__(256) void phaseB3_kernel(
    const int* __restrict__ bptrR, int* __restrict__ ptroutR, const u64* __restrict__ stageR,
    u32* __restrict__ ew0R, u32* __restrict__ ew1R,
    const int* __restrict__ bptrC, int* __restrict__ ptroutC, const u64* __restrict__ stageC,
    u32* __restrict__ ew0C, u32* __restrict__ ew1C, int n) {
  const int side = blockIdx.y;
  const int* bptr = side ? bptrC : bptrR;
  int* ptrout = side ? ptroutC : ptroutR;
  const u64* stage = side ? stageC : stageR;
  u32* ew0 = side ? ew0C : ew0R;
  u32* ew1 = side ? ew1C : ew1R;
  __shared__ u64 sorted[SCAP];
  __shared__ int cnt[128];
  __shared__ int pos[128];
  __shared__ int wtot[2];
  int t = threadIdx.x, b = blockIdx.x;
  int base_row = b*128;
  int base = bptr[b], endp = bptr[b+1];
  int total = endp - base;
  if (t < 128) cnt[t] = 0;
  __syncthreads();
  for (int k = base + t; k < endp; k += 256) {
    unsigned int lo = (unsigned int)__builtin_nontemporal_load(&stage[k]);
    atomicAdd(&cnt[(lo >> 16) & 127], 1);
  }
  __syncthreads();
  int lane = t & 63;
  if (t < 128) {
    int c = cnt[t], x = c;
    #pragma unroll
    for (int o = 1; o < 64; o <<= 1) { int y = __shfl_up(x, o); if (lane >= o) x += y; }
    if (lane == 63) wtot[t >> 6] = x;
    __syncthreads();
    int excl = (x - c) + ((t >= 64) ? wtot[0] : 0);
    pos[t] = excl;
    int rr = base_row + t;
    if (rr <= n) ptrout[rr] = base + excl;
  } else {
    __syncthreads();
  }
  __syncthreads();
  if (total <= SCAP) {
    for (int k = base + t; k < endp; k += 256) {
      u64 rec = __builtin_nontemporal_load(&stage[k]);
      int rel = ((unsigned int)rec >> 16) & 127;
      int idx = atomicAdd(&pos[rel], 1);
      sorted[idx] = rec;
    }
    __syncthreads();
    // per-row insertion sort by column (ascending) -> gather sweep locality in spmm
    if (t < 128) {
      int end = pos[t];            // after placement: end offset of row t
      int start = end - cnt[t];
      for (int i = start + 1; i < end; i++) {
        u64 key = sorted[i];
        u32 kc = (u32)key & 0xffffu;
        int j = i - 1;
        while (j >= start && ((u32)sorted[j] & 0xffffu) > kc) {
          sorted[j+1] = sorted[j];
          j--;
        }
        sorted[j+1] = key;
      }
    }
    __syncthreads();
    for (int idx = t; idx < total; idx += 256) {
      u64 rec = sorted[idx];
      unsigned int lo = (unsigned int)rec;
      float v = __uint_as_float((unsigned int)(rec >> 32));
      u32 col = lo & 0xffffu;
      u32 w0 = (lo & (1u<<24)) ? (u32)f2bf(v*KEEPV) : 0u;
      u32 w1 = (lo & (1u<<25)) ? (u32)f2bf(v*KEEPV) : 0u;
      int p = base + idx;
      ew0[p] = col | (w0 << 16);
      ew1[p] = col | (w1 << 16);
    }
  } else {
    for (int k = base + t; k < endp; k += 256) {
      u64 rec = stage[k];
      unsigned int lo = (unsigned int)rec;
      int rel = (lo >> 16) & 127;
      int p = base + atomicAdd(&pos[rel], 1);
      float v = __uint_as_float((unsigned int)(rec >> 32));
      u32 col = lo & 0xffffu;
      u32 w0 = (lo & (1u<<24)) ? (u32)f2bf(v*KEEPV) : 0u;
      u32 w1 = (lo & (1u<<25)) ? (u32)f2bf(v*KEEPV) : 0u;
      ew0[p] = col | (w0 << 16);
      ew1[p] = col | (w1 << 16);
    }
  }
}

// ---------------- pipelined gather row-dot (packed ew, 32-bit offsets) ----------------
__device__ __forceinline__ float spmm_row(const u32* __restrict__ ew,
                                          const ushort* __restrict__ Eb, int k0, int end, int lane) {
  float acc = 0.f;
  int nfull = (end - k0) >> 3;
  u32 e[8];
  if (nfull > 0) {
    #pragma unroll
    for (int u = 0; u < 8; u++) e[u] = __builtin_nontemporal_load(&ew[k0+u]);
    for (int b = 1; b < nfull; b++) {
      int kn = k0 + b*8;
      u32 en[8];
      #pragma unroll
      for (int u = 0; u < 8; u++) en[u] = __builtin_nontemporal_load(&ew[kn+u]);
      #pragma unroll
      for (int u = 0; u < 8; u++) {
        u32 off = ((e[u] & 0xffffu) << 6) | (u32)lane;
        acc += bf2f(e[u] >> 16)*bf2f(Eb[off]);
      }
      #pragma unroll
      for (int u = 0; u < 8; u++) e[u] = en[u];
    }
    #pragma unroll
    for (int u = 0; u < 8; u++) {
      u32 off = ((e[u] & 0xffffu) << 6) | (u32)lane;
      acc += bf2f(e[u] >> 16)*bf2f(Eb[off]);
    }
  }
  for (int k = k0 + nfull*8; k < end; k++) {
    u32 ek = __builtin_nontemporal_load(&ew[k]);
    u32 off = ((ek & 0xffffu) << 6) | (u32)lane;
    acc += bf2f(ek >> 16)*bf2f(Eb[off]);
  }
  return acc;
}

// ---------------- layer-0 SpMM (merged sides): bf16 gather -> bf16 Z ----------------
__global__ __launch_bounds__(256) void spmm_l0_kernel(
    const int* __restrict__ ptrR, const u32* __restrict__ ewR, const ushort* __restrict__ EbR, ushort* __restrict__ ZbR,
    const int* __restrict__ ptrC, const u32* __restrict__ ewC, const ushort* __restrict__ EbC, ushort* __restrict__ ZbC,
    int nrows) {
  const int side = blockIdx.y;
  const int* ptr = side ? ptrC : ptrR;
  const u32* ew = side ? ewC : ewR;
  const ushort* Eb = side ? EbC : EbR;
  ushort* Zb = side ? ZbC : ZbR;
  int lane = threadIdx.x & 63;
  int row = blockIdx.x*4 + (threadIdx.x >> 6);
  if (row >= nrows) return;
  float acc = spmm_row(ew, Eb, ptr[row], ptr[row+1], lane);
  Zb[(size_t)row*DIM + lane] = f2bf(acc);
}

// ---------------- layer-1 SpMM (merged sides) fused with E_sum -> bf16 out ----------------
__global__ __launch_bounds__(256) void spmm_l1_kernel(
    const int* __restrict__ ptrR, const u32* __restrict__ ewR, const ushort* __restrict__ ZbOR,
    const ushort* __restrict__ E0bR, const ushort* __restrict__ ZbSR, ushort* __restrict__ EoutR,
    const int* __restrict__ ptrC, const u32* __restrict__ ewC, const ushort* __restrict__ ZbOC,
    const ushort* __restrict__ E0bC, const ushort* __restrict__ ZbSC, ushort* __restrict__ EoutC,
    int nrows) {
  const int side = blockIdx.y;
  const int* ptr = side ? ptrC : ptrR;
  const u32* ew = side ? ewC : ewR;
  const ushort* ZbO = side ? ZbOC : ZbOR;
  const ushort* E0b = side ? E0bC : E0bR;
  const ushort* ZbS = side ? ZbSC : ZbSR;
  ushort* Eout = side ? EoutC : EoutR;
  int lane = threadIdx.x & 63;
  int row = blockIdx.x*4 + (threadIdx.x >> 6);
  if (row >= nrows) return;
  float acc = spmm_row(ew, ZbO, ptr[row], ptr[row+1], lane);
  size_t o = (size_t)row*DIM + lane;
  acc += bf2f(E0b[o]) + bf2f(ZbS[o]);
  Eout[o] = f2bf(acc);
}

// ---------------- matred (merged sides) stage 1: partial M = vrow @ (E0 + Zb) ----------------
__global__ __launch_bounds__(256) void matred2_kernel(
    const float* __restrict__ vrowA, const float* __restrict__ E0A, const ushort* __restrict__ ZbA, float* __restrict__ MpA,
    const float* __restrict__ vrowB, const float* __restrict__ E0B, const ushort* __restrict__ ZbB, float* __restrict__ MpB,
    int n) {
  const int side = blockIdx.y;
  const float* vrow = side ? vrowB : vrowA;
  const float* E0 = side ? E0B : E0A;
  const ushort* Zb = side ? ZbB : ZbA;
  float* Mpart = side ? MpB : MpA;
  __shared__ float vs[RNK*MCH];
  __shared__ float part[RNK*DIM];
  int t = threadIdx.x, lane = t & 63, w = t >> 6;
  int ci0 = blockIdx.x*MCH;
  int cnt = min(MCH, n - ci0);
  for (int idx = t; idx < RNK*DIM; idx += 256) part[idx] = 0.f;
  for (int idx = t; idx < RNK*MCH; idx += 256) {
    int r = idx >> 8, i = idx & (MCH-1);
    vs[idx] = (i < cnt) ? __builtin_nontemporal_load(&vrow[(size_t)r*n + ci0 + i]) : 0.f;
  }
  __syncthreads();
  float acc[RNK];
  #pragma unroll
  for (int r = 0; r < RNK; r++) acc[r] = 0.f;
  int iw0 = w*64;
  for (int ii = 0; ii < 64; ii += 4) {
    int i = iw0 + ii;
    int gi = ci0 + i;
    float x0 = 0.f, x1 = 0.f, x2 = 0.f, x3 = 0.f;
    if (i+0 < cnt) x0 = E0[(size_t)(gi+0)*DIM + lane] + bf2f(Zb[(size_t)(gi+0)*DIM + lane]);
    if (i+1 < cnt) x1 = E0[(size_t)(gi+1)*DIM + lane] + bf2f(Zb[(size_t)(gi+1)*DIM + lane]);
    if (i+2 < cnt) x2 = E0[(size_t)(gi+2)*DIM + lane] + bf2f(Zb[(size_t)(gi+2)*DIM + lane]);
    if (i+3 < cnt) x3 = E0[(size_t)(gi+3)*DIM + lane] + bf2f(Zb[(size_t)(gi+3)*DIM + lane]);
    #pragma unroll
    for (int r = 0; r < RNK; r++) {
      float4 v4 = *(const float4*)&vs[r*MCH + i];
      acc[r] += v4.x*x0 + v4.y*x1 + v4.z*x2 + v4.w*x3;
    }
  }
  #pragma unroll
  for (int r = 0; r < RNK; r++) atomicAdd(&part[r*DIM + lane], acc[r]);
  __syncthreads();
  float* dst = Mpart + (size_t)blockIdx.x*(RNK*DIM);
  for (int idx = t; idx < RNK*DIM; idx += 256) dst[idx] = part[idx];
}

// ---------------- matred stage 2 (merged): reduce partials ----------------
__global__ __launch_bounds__(256) void mreduce_kernel(const float* __restrict__ MpA, float* __restrict__ MA,
                                                      const float* __restrict__ MpB, float* __restrict__ MB, int nblk) {
  const float* Mpart = blockIdx.y ? MpB : MpA;
  float* M = blockIdx.y ? MB : MA;
  int idx = blockIdx.x*256 + threadIdx.x;
  if (idx < RNK*DIM) {
    float s = 0.f;
    for (int b = 0; b < nblk; b++) s += Mpart[(size_t)b*(RNK*DIM) + idx];
    M[idx] = s;
  }
}

// ---------------- G rows at sampled ids (merged sides; fp32 + bf16 out) ----------------
__global__ __launch_bounds__(256) void gsmall_kernel(
    const int* __restrict__ idsA, const float* __restrict__ E0A, const float* __restrict__ mulA,
    const float* __restrict__ MA, float* __restrict__ outA, ushort* __restrict__ outbA,
    const int* __restrict__ idsB, const float* __restrict__ E0B, const float* __restrict__ mulB,
    const float* __restrict__ MB, float* __restrict__ outB, ushort* __restrict__ outbB) {
  const int side = blockIdx.y;
  const int* ids = side ? idsB : idsA;
  const float* E0 = side ? E0B : E0A;
  const float* mul = side ? mulB : mulA;
  const float* M = side ? MB : MA;
  float* out = side ? outB : outA;
  ushort* outb = side ? outbB : outbA;
  __shared__ float Ms[RNK*DIM];
  int t = threadIdx.x;
  for (int i = t; i < RNK*DIM; i += 256) Ms[i] = M[i];
  __syncthreads();
  int b = blockIdx.x*4 + (t >> 6), lane = t & 63;
  int u = ids[b];
  float a = E0[(size_t)u*DIM + lane];
  #pragma unroll
  for (int r = 0; r < RNK; r++) a += mul[(size_t)u*RNK + r]*Ms[r*DIM + lane];
  out[(size_t)b*DIM + lane] = a;
  outb[(size_t)b*DIM + lane] = f2bf(a);
}

// ---------------- fp32 -> bf16 conversion fused with sum-of-squares (merged; 1 atomic/block) ----------------
__global__ __launch_bounds__(256) void convsq_kernel(const float* __restrict__ inA, ushort* __restrict__ outA,
                                                     const float* __restrict__ inB, ushort* __restrict__ outB,
                                                     int n4, float* __restrict__ acc) {
  const float* in = blockIdx.y ? inB : inA;
  ushort* out = blockIdx.y ? outB : outA;
  __shared__ float ls[4];
  int t = threadIdx.x;
  int idx = blockIdx.x*256 + t;
  int stride = gridDim.x*256;
  float s = 0.f;
  for (int i = idx; i < n4; i += stride) {
    float4 v = *(const float4*)&in[(size_t)i*4];
    ushort4 o;
    o.x = f2bf(v.x); o.y = f2bf(v.y); o.z = f2bf(v.z); o.w = f2bf(v.w);
    *(ushort4*)&out[(size_t)i*4] = o;
    s += v.x*v.x + v.y*v.y + v.z*v.z + v.w*v.w;
  }
  #pragma unroll
  for (int o = 32; o > 0; o >>= 1) s += __shfl_xor(s, o);
  if ((t & 63) == 0) ls[t >> 6] = s;
  __syncthreads();
  if (t == 0) atomicAdd(acc, ls[0] + ls[1] + ls[2] + ls[3]);
}

// ---------------- bf16 MFMA fused GEMM + exp + row-sum (merged sides; 2 b-tiles/block) ----------------
__global__ __launch_bounds__(256) void lse_mfma_kernel(
    const ushort* __restrict__ Ag, const ushort* __restrict__ Xg, float* __restrict__ seg,
    const ushort* __restrict__ Ad, const ushort* __restrict__ Xd, float* __restrict__ sed,
    int nj) {
  const ushort* A = blockIdx.y ? Ad : Ag;
  const ushort* X = blockIdx.y ? Xd : Xg;
  float* sumexp = blockIdx.y ? sed : seg;
  __shared__ __align__(16) ushort Xs[64*68];
  int t = threadIdx.x, lane = t & 63, w = t >> 6;
  int bt = blockIdx.x & 15, js = blockIdx.x >> 4;
  int b0 = bt*128;
  int m = lane & 15, q = lane >> 4;
  const ushort* Arow0 = A + (size_t)(b0 + w*16 + m)*DIM + q*8;
  const ushort* Arow1 = A + (size_t)(b0 + 64 + w*16 + m)*DIM + q*8;
  bfrag a00 = *(const bfrag*)(Arow0);
  bfrag a01 = *(const bfrag*)(Arow0 + 32);
  bfrag a10 = *(const bfrag*)(Arow1);
  bfrag a11 = *(const bfrag*)(Arow1 + 32);
  float rs[2][4] = {{0.f,0.f,0.f,0.f},{0.f,0.f,0.f,0.f}};
  int njt = (nj + 63) >> 6;
  for (int jt = js; jt < njt; jt += NSL) {
    int j0 = jt << 6;
    __syncthreads();
    for (int c = t; c < 512; c += 256) {
      int r = c >> 3, k8 = (c & 7) << 3;
      int j = j0 + r;
      ushort4 v0 = {0,0,0,0}, v1 = {0,0,0,0};
      if (j < nj) {
        const ushort4* src = (const ushort4*)(X + (size_t)j*DIM + k8);
        v0 = src[0]; v1 = src[1];
      }
      *(ushort4*)&Xs[r*68 + k8]     = v0;
      *(ushort4*)&Xs[r*68 + k8 + 4] = v1;
    }
    __syncthreads();
    #pragma unroll
    for (int jq = 0; jq < 4; jq++) {
      int jr = jq*16 + m;
      union { bfrag f; uint2 u2[2]; } B0, B1;
      B0.u2[0] = *(const uint2*)&Xs[jr*68 + q*8];
      B0.u2[1] = *(const uint2*)&Xs[jr*68 + q*8 + 4];
      B1.u2[0] = *(const uint2*)&Xs[jr*68 + 32 + q*8];
      B1.u2[1] = *(const uint2*)&Xs[jr*68 + 32 + q*8 + 4];
      f32x4 acc0 = {0.f, 0.f, 0.f, 0.f};
      f32x4 acc1 = {0.f, 0.f, 0.f, 0.f};
      acc0 = __builtin_amdgcn_mfma_f32_16x16x32_bf16(a00, B0.f, acc0, 0, 0, 0);
      acc0 = __builtin_amdgcn_mfma_f32_16x16x32_bf16(a01, B1.f, acc0, 0, 0, 0);
      acc1 = __builtin_amdgcn_mfma_f32_16x16x32_bf16(a10, B0.f, acc1, 0, 0, 0);
      acc1 = __builtin_amdgcn_mfma_f32_16x16x32_bf16(a11, B1.f, acc1, 0, 0, 0);
      int jg = j0 + jr;
      if (jg < nj) {
        rs[0][0] += __expf(acc0[0]*INVT);
        rs[0][1] += __expf(acc0[1]*INVT);
        rs[0][2] += __expf(acc0[2]*INVT);
        rs[0][3] += __expf(acc0[3]*INVT);
        rs[1][0] += __expf(acc1[0]*INVT);
        rs[1][1] += __expf(acc1[1]*INVT);
        rs[1][2] += __expf(acc1[2]*INVT);
        rs[1][3] += __expf(acc1[3]*INVT);
      }
    }
  }
  #pragma unroll
  for (int h = 0; h < 2; h++) {
    #pragma unroll
    for (int o = 1; o < 16; o <<= 1) {
      rs[h][0] += __shfl_xor(rs[h][0], o);
      rs[h][1] += __shfl_xor(rs[h][1], o);
      rs[h][2] += __shfl_xor(rs[h][2], o);
      rs[h][3] += __shfl_xor(rs[h][3], o);
    }
  }
  if (m == 0) {
    #pragma unroll
    for (int h = 0; h < 2; h++) {
      float* dst = &sumexp[b0 + h*64 + w*16 + q*4];
      atomicAdd(&dst[0], rs[h][0]);
      atomicAdd(&dst[1], rs[h][1]);
      atomicAdd(&dst[2], rs[h][2]);
      atomicAdd(&dst[3], rs[h][3]);
    }
  }
}

// ---------------- per-sample terms (bf16 E_sum tables); 3 atomics/block ----------------
__global__ __launch_bounds__(256) void perb_kernel(const int* __restrict__ uids, const int* __restrict__ iids,
    const int* __restrict__ pos, const int* __restrict__ neg,
    const float* __restrict__ Ggu, const float* __restrict__ Gdi,
    const ushort* __restrict__ Egs_b, const ushort* __restrict__ Eds_b,
    const float* __restrict__ seg, const float* __restrict__ sed,
    float* __restrict__ accs) {
  __shared__ float lsum[3][4];
  int t = threadIdx.x, lane = t & 63, w = t >> 6;
  int b = blockIdx.x*4 + w;
  int u = uids[b], it = iids[b], p = pos[b], ng = neg[b];
  float egu = bf2f(Egs_b[(size_t)u*DIM + lane]);
  float d1 = Ggu[(size_t)b*DIM + lane]*egu;
  float d2 = Gdi[(size_t)b*DIM + lane]*bf2f(Eds_b[(size_t)it*DIM + lane]);
  float d3 = egu*bf2f(Eds_b[(size_t)p*DIM + lane]);
  float d4 = egu*bf2f(Eds_b[(size_t)ng*DIM + lane]);
  #pragma unroll
  for (int o = 32; o > 0; o >>= 1) {
    d1 += __shfl_xor(d1, o);
    d2 += __shfl_xor(d2, o);
    d3 += __shfl_xor(d3, o);
    d4 += __shfl_xor(d4, o);
  }
  if (lane == 0) {
    float pterm = fminf(fmaxf(d1*INVT, -5.f), 5.f) + fminf(fmaxf(d2*INVT, -5.f), 5.f);
    float diff = d3 - d4;
    lsum[0][w] = pterm;
    lsum[1][w] = log1pf(expf(-diff));
    lsum[2][w] = logf(seg[b] + 1e-8f) + logf(sed[b] + 1e-8f);
  }
  __syncthreads();
  if (t < 3) atomicAdd(&accs[t], lsum[t][0] + lsum[t][1] + lsum[t][2] + lsum[t][3]);
}

__global__ void final_kernel(const float* __restrict__ accs, float* __restrict__ out) {
  float posm = accs[0]*(1.f/BSZ);
  float lr   = accs[1]*(1.f/BSZ);
  float negm = accs[2]*(1.f/BSZ);
  float reg  = 1e-7f*accs[3];
  float l1ls = 0.2f*(negm - posm);
  out[0] = lr + l1ls + reg;
  out[1] = lr;
  out[2] = l1ls;
}

extern "C" void kernel_launch(void* const* d_in, const int* in_sizes, int n_in,
                              void* d_out, int out_size, void* d_ws, size_t ws_size,
                              hipStream_t stream) {
  (void)in_sizes; (void)n_in; (void)out_size;
  const int*   uids = (const int*)d_in[0];
  const int*   iids = (const int*)d_in[1];
  const int*   pos  = (const int*)d_in[2];
  const int*   neg  = (const int*)d_in[3];
  const float* Eg0  = (const float*)d_in[4];
  const float* Ed0  = (const float*)d_in[5];
  const int*   rows = (const int*)d_in[6];
  const int*   cols = (const int*)d_in[7];
  const float* vals = (const float*)d_in[8];
  const float* gms  = (const float*)d_in[9];
  const float* vms  = (const float*)d_in[10];
  const float* ut   = (const float*)d_in[11];
  const float* vt   = (const float*)d_in[12];
  const float* drop = (const float*)d_in[13];
  float* out = (float*)d_out;

  float* ws = (float*)d_ws;
  const size_t ED = (size_t)N_Gc*DIM;  // 3.2M
  float* REG_A = ws;           // [ED] : stage_r -> (Zg0_b, Zd0_b)
  float* REG_B = REG_A + ED;   // [ED] : stage_c -> (Eg0_b,Ed0_b) -> (Egs_b,Eds_b)
  int* ptr_r = (int*)(REG_B + ED);
  int* ptr_c = ptr_r + (N_Gc + 1);
  int* bptr_r = ptr_c + (N_Dc + 1);
  int* bptr_c = bptr_r + (NBK3 + 1);
  int* cntR = bptr_c + (NBK3 + 1);
  int* cntC = cntR + NBK3*NBLK;
  int* cbR  = cntC + NBK3*NBLK;
  int* cbC  = cbR + NBK3*NBLK;
  u32* ew_r0 = (u32*)(cbC + NBK3*NBLK);
  u32* ew_r1 = ew_r0 + NNZc;
  u32* ew_c0 = ew_r1 + NNZc;
  u32* ew_c1 = ew_c0 + NNZc;
  float* Ggu = (float*)(ew_c1 + NNZc);
  float* Gdi = Ggu + (size_t)BSZ*DIM;
  ushort* Ggu_b = (ushort*)(Gdi + (size_t)BSZ*DIM);
  ushort* Gdi_b = Ggu_b + (size_t)BSZ*DIM;
  float* Mg  = (float*)(Gdi_b + (size_t)BSZ*DIM);
  float* Md  = Mg + RNK*DIM;
  float* seg = Md + RNK*DIM;            // zeroed zone starts here
  float* sed = seg + BSZ;
  float* accs = sed + BSZ;              // 16 floats
  float* MpG = accs + 16;               // matred partials: MBLK*2048 each
  float* MpD = MpG + (size_t)MBLK*RNK*DIM;

  // overlays (lifetimes are disjoint on the serial stream):
  u64* stage_r = (u64*)REG_A;                   // phaseA..phaseB
  u64* stage_c = (u64*)REG_B;                   // phaseA..phaseB
  ushort* Zg0_b = (ushort*)REG_A;               // l0..matred2 (after stage_r dead)
  ushort* Zd0_b = Zg0_b + ED;
  ushort* Eg0_b = (ushort*)REG_B;               // conv..l1 (after stage_c dead)
  ushort* Ed0_b = Eg0_b + ED;
  ushort* Egs_b = (ushort*)REG_B;               // l1..end (same-index overwrite of Eg0_b in l1: thread-local RAW, safe)
  ushort* Eds_b = Egs_b + ED;

  size_t need = ((char*)(MpD + (size_t)MBLK*RNK*DIM)) - ((char*)d_ws);
  if (ws_size < need) return;

  hipMemsetAsync(seg, 0, sizeof(float)*(2*BSZ + 16), stream);

  hist3_kernel<<<NBLK, 256, 0, stream>>>(rows, cols, cntR, cntC);
  cscan2_kernel<<<2, 1024, 0, stream>>>(cntR, cbR, bptr_r, cntC, cbC, bptr_c);
  phaseA2_kernel<<<NBLK, 256, 0, stream>>>(rows, cols, vals, drop, cbR, cbC, stage_r, stage_c);
  phaseB3_kernel<<<dim3(NBK3, 2), 256, 0, stream>>>(
      bptr_r, ptr_r, stage_r, ew_r0, ew_r1,
      bptr_c, ptr_c, stage_c, ew_c0, ew_c1, N_Gc);

  // bf16 copies of the layer-0 gather tables + fused L2-reg sum-of-squares
  int n4 = (int)(ED/4);
  convsq_kernel<<<dim3(1024, 2), 256, 0, stream>>>(Eg0, Eg0_b, Ed0, Ed0_b, n4, accs + 3);

  int spmm_blocks = (N_Gc + 3)/4;
  // layer 0: Zg = A0 @ Ed0 ; Zd = A0^T @ Eg0  (bf16 gathers, bf16-only outputs)
  spmm_l0_kernel<<<dim3(spmm_blocks, 2), 256, 0, stream>>>(
      ptr_r, ew_r0, Ed0_b, Zg0_b,
      ptr_c, ew_c0, Eg0_b, Zd0_b, N_Gc);
  // layer 1 fused: Egs = Eg0 + Zg0 + A1 @ Zd0 -> bf16 ; Eds likewise (all-bf16 adds)
  spmm_l1_kernel<<<dim3(spmm_blocks, 2), 256, 0, stream>>>(
      ptr_r, ew_r1, Zd0_b, Eg0_b, Zg0_b, Egs_b,
      ptr_c, ew_c1, Zg0_b, Ed0_b, Zd0_b, Eds_b, N_Gc);

  // Mg = vt @ (Ed0 + Zd0) ; Md = ut @ (Eg0 + Zg0) — two-stage, no global atomics
  matred2_kernel<<<dim3(MBLK, 2), 256, 0, stream>>>(
      vt, Ed0, Zd0_b, MpG,
      ut, Eg0, Zg0_b, MpD, N_Dc);
  mreduce_kernel<<<dim3((RNK*DIM + 255)/256, 2), 256, 0, stream>>>(MpG, Mg, MpD, Md, MBLK);

  gsmall_kernel<<<dim3(BSZ/4, 2), 256, 0, stream>>>(
      uids, Eg0, gms, Mg, Ggu, Ggu_b,
      iids, Ed0, vms, Md, Gdi, Gdi_b);

  lse_mfma_kernel<<<dim3(16*NSL, 2), 256, 0, stream>>>(Ggu_b, Egs_b, seg, Gdi_b, Eds_b, sed, N_Gc);

  perb_kernel<<<BSZ/4, 256, 0, stream>>>(uids, iids, pos, neg, Ggu, Gdi, Egs_b, Eds_b, seg, sed, accs);
  final_kernel<<<1, 1, 0, stream>>>(accs, out);
}

// Round 16
// 611.127 us; speedup vs baseline: 1.2880x; 1.2880x over previous
//
#include <hip/hip_runtime.h>
#include <hip/hip_bf16.h>
#include <math.h>

#define N_Gc 50000
#define N_Dc 50000
#define DIM 64
#define RNK 32
#define NNZc 1600000
#define BSZ 2048
#define KEEPV (1.0f/0.9f)
#define INVT 5.0f
#define NBK3 391     // (50000+127)/128 buckets of 128 rows
#define NBLK 200     // NNZ/EPB scatter blocks
#define NSL 48       // j-slices for lse grid
#define EPB 8000     // edges per block (hist3 + phaseA)
#define MCH 256      // matred i-chunk per block
#define MBLK 196     // ceil(50000/256)
#define SCAP 6144    // LDS sort capacity (records) in phaseB3

typedef __attribute__((ext_vector_type(8))) short bfrag;
typedef __attribute__((ext_vector_type(4))) float f32x4;
typedef unsigned long long u64;
typedef unsigned int u32;

__device__ inline ushort f2bf(float f) {
  union { float f; unsigned int u; } v; v.f = f;
  unsigned int r = (v.u + 0x7fffu + ((v.u >> 16) & 1u)) >> 16;
  return (ushort)r;
}
__device__ inline float bf2f(u32 u) {
  union { unsigned int i; float f; } v; v.i = u << 16;
  return v.f;
}

// ---------------- hist3: per-(bucket,block) dense counts, no global atomics ----------------
__global__ __launch_bounds__(256) void hist3_kernel(const int* __restrict__ rows, const int* __restrict__ cols,
                                                    int* __restrict__ cntR, int* __restrict__ cntC) {
  __shared__ int lh_r[NBK3];
  __shared__ int lh_c[NBK3];
  int t = threadIdx.x, blk = blockIdx.x;
  for (int j = t; j < NBK3; j += 256) { lh_r[j] = 0; lh_c[j] = 0; }
  __syncthreads();
  int e0 = blk*EPB;
  for (int i = e0 + t; i < e0 + EPB; i += 256) {
    atomicAdd(&lh_r[__builtin_nontemporal_load(&rows[i]) >> 7], 1);
    atomicAdd(&lh_c[__builtin_nontemporal_load(&cols[i]) >> 7], 1);
  }
  __syncthreads();
  for (int j = t; j < NBK3; j += 256) {
    cntR[j*NBLK + blk] = lh_r[j];
    cntC[j*NBLK + blk] = lh_c[j];
  }
}

// ---------------- cscan2: prefix over [bucket][block] counts -> per-block bases + bucket ptr ----------------
__global__ __launch_bounds__(1024) void cscan2_kernel(const int* __restrict__ cntA, int* __restrict__ cbA, int* __restrict__ bpA,
                                                      const int* __restrict__ cntB, int* __restrict__ cbB, int* __restrict__ bpB) {
  const int n = NBK3*NBLK;
  const int* cnt = blockIdx.x ? cntB : cntA;
  int* cb = blockIdx.x ? cbB : cbA;
  int* bp = blockIdx.x ? bpB : bpA;
  __shared__ int wsum[16];
  int t = threadIdx.x, lane = t & 63, w = t >> 6;
  int carry = 0;
  for (int base = 0; base < n; base += 1024) {
    int i = base + t;
    int v = (i < n) ? cnt[i] : 0;
    int x = v;
    #pragma unroll
    for (int o = 1; o < 64; o <<= 1) { int y = __shfl_up(x, o); if (lane >= o) x += y; }
    if (lane == 63) wsum[w] = x;
    __syncthreads();
    if (t < 16) {
      int s = wsum[t];
      #pragma unroll
      for (int o = 1; o < 16; o <<= 1) { int y = __shfl_up(s, o); if (t >= o) s += y; }
      wsum[t] = s;
    }
    __syncthreads();
    int wpre = (w == 0) ? 0 : wsum[w-1];
    int total = wsum[15];
    int ex = carry + wpre + (x - v);
    if (i < n) {
      cb[i] = ex;
      if (i % NBLK == 0) bp[i/NBLK] = ex;
    }
    carry += total;
    __syncthreads();
  }
  if (t == 0) bp[NBK3] = carry;
}

// ---------------- phase A: single-pass deterministic scatter (no global atomics) ----------------
// record u64: lo32 = other_id[0:15] | rel[16:23] | d0<<24 | d1<<25 ; hi32 = val bits
__global__ __launch_bounds__(256) void phaseA2_kernel(const int* __restrict__ rows, const int* __restrict__ cols,
    const float* __restrict__ vals, const float* __restrict__ drop,
    const int* __restrict__ cbR, const int* __restrict__ cbC,
    u64* __restrict__ stage_r, u64* __restrict__ stage_c) {
  __shared__ int cnt_r[NBK3], cnt_c[NBK3];
  __shared__ int base_r[NBK3], base_c[NBK3];
  int t = threadIdx.x, blk = blockIdx.x;
  for (int j = t; j < NBK3; j += 256) {
    cnt_r[j] = 0; cnt_c[j] = 0;
    base_r[j] = cbR[j*NBLK + blk];
    base_c[j] = cbC[j*NBLK + blk];
  }
  __syncthreads();
  int e0 = blk*EPB;
  for (int i = e0 + t; i < e0 + EPB; i += 256) {
    int r = __builtin_nontemporal_load(&rows[i]);
    int c = __builtin_nontemporal_load(&cols[i]);
    u64 vb = (u64)__float_as_uint(__builtin_nontemporal_load(&vals[i])) << 32;
    unsigned int dr0 = (__builtin_nontemporal_load(&drop[i]) > 0.1f) ? (1u<<24) : 0u;
    unsigned int dc0 = (__builtin_nontemporal_load(&drop[(size_t)NNZc + i]) > 0.1f) ? (1u<<24) : 0u;
    unsigned int dr1 = (__builtin_nontemporal_load(&drop[2*(size_t)NNZc + i]) > 0.1f) ? (1u<<25) : 0u;
    unsigned int dc1 = (__builtin_nontemporal_load(&drop[3*(size_t)NNZc + i]) > 0.1f) ? (1u<<25) : 0u;
    int br = r >> 7, bc = c >> 7;
    int p = base_r[br] + atomicAdd(&cnt_r[br], 1);
    stage_r[p] = vb | (unsigned int)c | ((unsigned int)(r & 127) << 16) | dr0 | dr1;
    int q = base_c[bc] + atomicAdd(&cnt_c[bc], 1);
    stage_c[q] = vb | (unsigned int)r | ((unsigned int)(c & 127) << 16) | dc0 | dc1;
  }
}

// ---------------- phase B3 (merged sides): sort into LDS, sequential writeout of packed ew ----------------
// ew: col[0:15] | bf16(weight)[16:31]
__global__ __launch_bounds__(256) void phaseB3_kernel(
    const int* __restrict__ bptrR, int* __restrict__ ptroutR, const u64* __restrict__ stageR,
    u32* __restrict__ ew0R, u32* __restrict__ ew1R,
    const int* __restrict__ bptrC, int* __restrict__ ptroutC, const u64* __restrict__ stageC,
    u32* __restrict__ ew0C, u32* __restrict__ ew1C, int n) {
  const int side = blockIdx.y;
  const int* bptr = side ? bptrC : bptrR;
  int* ptrout = side ? ptroutC : ptroutR;
  const u64* stage = side ? stageC : stageR;
  u32* ew0 = side ? ew0C : ew0R;
  u32* ew1 = side ? ew1C : ew1R;
  __shared__ u64 sorted[SCAP];
  __shared__ int cnt[128];
  __shared__ int pos[128];
  __shared__ int wtot[2];
  int t = threadIdx.x, b = blockIdx.x;
  int base_row = b*128;
  int base = bptr[b], endp = bptr[b+1];
  int total = endp - base;
  if (t < 128) cnt[t] = 0;
  __syncthreads();
  for (int k = base + t; k < endp; k += 256) {
    unsigned int lo = (unsigned int)__builtin_nontemporal_load(&stage[k]);
    atomicAdd(&cnt[(lo >> 16) & 127], 1);
  }
  __syncthreads();
  int lane = t & 63;
  if (t < 128) {
    int c = cnt[t], x = c;
    #pragma unroll
    for (int o = 1; o < 64; o <<= 1) { int y = __shfl_up(x, o); if (lane >= o) x += y; }
    if (lane == 63) wtot[t >> 6] = x;
    __syncthreads();
    int excl = (x - c) + ((t >= 64) ? wtot[0] : 0);
    pos[t] = excl;
    int rr = base_row + t;
    if (rr <= n) ptrout[rr] = base + excl;
  } else {
    __syncthreads();
  }
  __syncthreads();
  if (total <= SCAP) {
    for (int k = base + t; k < endp; k += 256) {
      u64 rec = __builtin_nontemporal_load(&stage[k]);
      int rel = ((unsigned int)rec >> 16) & 127;
      int idx = atomicAdd(&pos[rel], 1);
      sorted[idx] = rec;
    }
    __syncthreads();
    for (int idx = t; idx < total; idx += 256) {
      u64 rec = sorted[idx];
      unsigned int lo = (unsigned int)rec;
      float v = __uint_as_float((unsigned int)(rec >> 32));
      u32 col = lo & 0xffffu;
      u32 w0 = (lo & (1u<<24)) ? (u32)f2bf(v*KEEPV) : 0u;
      u32 w1 = (lo & (1u<<25)) ? (u32)f2bf(v*KEEPV) : 0u;
      int p = base + idx;
      ew0[p] = col | (w0 << 16);
      ew1[p] = col | (w1 << 16);
    }
  } else {
    for (int k = base + t; k < endp; k += 256) {
      u64 rec = stage[k];
      unsigned int lo = (unsigned int)rec;
      int rel = (lo >> 16) & 127;
      int p = base + atomicAdd(&pos[rel], 1);
      float v = __uint_as_float((unsigned int)(rec >> 32));
      u32 col = lo & 0xffffu;
      u32 w0 = (lo & (1u<<24)) ? (u32)f2bf(v*KEEPV) : 0u;
      u32 w1 = (lo & (1u<<25)) ? (u32)f2bf(v*KEEPV) : 0u;
      ew0[p] = col | (w0 << 16);
      ew1[p] = col | (w1 << 16);
    }
  }
}

// ---------------- pipelined gather row-dot (packed ew, 32-bit offsets) ----------------
__device__ __forceinline__ float spmm_row(const u32* __restrict__ ew,
                                          const ushort* __restrict__ Eb, int k0, int end, int lane) {
  float acc = 0.f;
  int nfull = (end - k0) >> 3;
  u32 e[8];
  if (nfull > 0) {
    #pragma unroll
    for (int u = 0; u < 8; u++) e[u] = __builtin_nontemporal_load(&ew[k0+u]);
    for (int b = 1; b < nfull; b++) {
      int kn = k0 + b*8;
      u32 en[8];
      #pragma unroll
      for (int u = 0; u < 8; u++) en[u] = __builtin_nontemporal_load(&ew[kn+u]);
      #pragma unroll
      for (int u = 0; u < 8; u++) {
        u32 off = ((e[u] & 0xffffu) << 6) | (u32)lane;
        acc += bf2f(e[u] >> 16)*bf2f(Eb[off]);
      }
      #pragma unroll
      for (int u = 0; u < 8; u++) e[u] = en[u];
    }
    #pragma unroll
    for (int u = 0; u < 8; u++) {
      u32 off = ((e[u] & 0xffffu) << 6) | (u32)lane;
      acc += bf2f(e[u] >> 16)*bf2f(Eb[off]);
    }
  }
  for (int k = k0 + nfull*8; k < end; k++) {
    u32 ek = __builtin_nontemporal_load(&ew[k]);
    u32 off = ((ek & 0xffffu) << 6) | (u32)lane;
    acc += bf2f(ek >> 16)*bf2f(Eb[off]);
  }
  return acc;
}

// ---------------- layer-0 SpMM (merged sides): bf16 gather -> bf16 Z ----------------
__global__ __launch_bounds__(256) void spmm_l0_kernel(
    const int* __restrict__ ptrR, const u32* __restrict__ ewR, const ushort* __restrict__ EbR, ushort* __restrict__ ZbR,
    const int* __restrict__ ptrC, const u32* __restrict__ ewC, const ushort* __restrict__ EbC, ushort* __restrict__ ZbC,
    int nrows) {
  const int side = blockIdx.y;
  const int* ptr = side ? ptrC : ptrR;
  const u32* ew = side ? ewC : ewR;
  const ushort* Eb = side ? EbC : EbR;
  ushort* Zb = side ? ZbC : ZbR;
  int lane = threadIdx.x & 63;
  int row = blockIdx.x*4 + (threadIdx.x >> 6);
  if (row >= nrows) return;
  float acc = spmm_row(ew, Eb, ptr[row], ptr[row+1], lane);
  Zb[(size_t)row*DIM + lane] = f2bf(acc);
}

// ---------------- layer-1 SpMM (merged sides) fused with E_sum -> bf16 out ----------------
__global__ __launch_bounds__(256) void spmm_l1_kernel(
    const int* __restrict__ ptrR, const u32* __restrict__ ewR, const ushort* __restrict__ ZbOR,
    const ushort* __restrict__ E0bR, const ushort* __restrict__ ZbSR, ushort* __restrict__ EoutR,
    const int* __restrict__ ptrC, const u32* __restrict__ ewC, const ushort* __restrict__ ZbOC,
    const ushort* __restrict__ E0bC, const ushort* __restrict__ ZbSC, ushort* __restrict__ EoutC,
    int nrows) {
  const int side = blockIdx.y;
  const int* ptr = side ? ptrC : ptrR;
  const u32* ew = side ? ewC : ewR;
  const ushort* ZbO = side ? ZbOC : ZbOR;
  const ushort* E0b = side ? E0bC : E0bR;
  const ushort* ZbS = side ? ZbSC : ZbSR;
  ushort* Eout = side ? EoutC : EoutR;
  int lane = threadIdx.x & 63;
  int row = blockIdx.x*4 + (threadIdx.x >> 6);
  if (row >= nrows) return;
  float acc = spmm_row(ew, ZbO, ptr[row], ptr[row+1], lane);
  size_t o = (size_t)row*DIM + lane;
  acc += bf2f(E0b[o]) + bf2f(ZbS[o]);
  Eout[o] = f2bf(acc);
}

// ---------------- matred (merged sides) stage 1: partial M = vrow @ (E0 + Zb) ----------------
__global__ __launch_bounds__(256) void matred2_kernel(
    const float* __restrict__ vrowA, const float* __restrict__ E0A, const ushort* __restrict__ ZbA, float* __restrict__ MpA,
    const float* __restrict__ vrowB, const float* __restrict__ E0B, const ushort* __restrict__ ZbB, float* __restrict__ MpB,
    int n) {
  const int side = blockIdx.y;
  const float* vrow = side ? vrowB : vrowA;
  const float* E0 = side ? E0B : E0A;
  const ushort* Zb = side ? ZbB : ZbA;
  float* Mpart = side ? MpB : MpA;
  __shared__ float vs[RNK*MCH];
  __shared__ float part[RNK*DIM];
  int t = threadIdx.x, lane = t & 63, w = t >> 6;
  int ci0 = blockIdx.x*MCH;
  int cnt = min(MCH, n - ci0);
  for (int idx = t; idx < RNK*DIM; idx += 256) part[idx] = 0.f;
  for (int idx = t; idx < RNK*MCH; idx += 256) {
    int r = idx >> 8, i = idx & (MCH-1);
    vs[idx] = (i < cnt) ? __builtin_nontemporal_load(&vrow[(size_t)r*n + ci0 + i]) : 0.f;
  }
  __syncthreads();
  float acc[RNK];
  #pragma unroll
  for (int r = 0; r < RNK; r++) acc[r] = 0.f;
  int iw0 = w*64;
  for (int ii = 0; ii < 64; ii += 4) {
    int i = iw0 + ii;
    int gi = ci0 + i;
    float x0 = 0.f, x1 = 0.f, x2 = 0.f, x3 = 0.f;
    if (i+0 < cnt) x0 = E0[(size_t)(gi+0)*DIM + lane] + bf2f(Zb[(size_t)(gi+0)*DIM + lane]);
    if (i+1 < cnt) x1 = E0[(size_t)(gi+1)*DIM + lane] + bf2f(Zb[(size_t)(gi+1)*DIM + lane]);
    if (i+2 < cnt) x2 = E0[(size_t)(gi+2)*DIM + lane] + bf2f(Zb[(size_t)(gi+2)*DIM + lane]);
    if (i+3 < cnt) x3 = E0[(size_t)(gi+3)*DIM + lane] + bf2f(Zb[(size_t)(gi+3)*DIM + lane]);
    #pragma unroll
    for (int r = 0; r < RNK; r++) {
      float4 v4 = *(const float4*)&vs[r*MCH + i];
      acc[r] += v4.x*x0 + v4.y*x1 + v4.z*x2 + v4.w*x3;
    }
  }
  #pragma unroll
  for (int r = 0; r < RNK; r++) atomicAdd(&part[r*DIM + lane], acc[r]);
  __syncthreads();
  float* dst = Mpart + (size_t)blockIdx.x*(RNK*DIM);
  for (int idx = t; idx < RNK*DIM; idx += 256) dst[idx] = part[idx];
}

// ---------------- matred stage 2 (merged): reduce partials ----------------
__global__ __launch_bounds__(256) void mreduce_kernel(const float* __restrict__ MpA, float* __restrict__ MA,
                                                      const float* __restrict__ MpB, float* __restrict__ MB, int nblk) {
  const float* Mpart = blockIdx.y ? MpB : MpA;
  float* M = blockIdx.y ? MB : MA;
  int idx = blockIdx.x*256 + threadIdx.x;
  if (idx < RNK*DIM) {
    float s = 0.f;
    for (int b = 0; b < nblk; b++) s += Mpart[(size_t)b*(RNK*DIM) + idx];
    M[idx] = s;
  }
}

// ---------------- G rows at sampled ids (merged sides; fp32 + bf16 out) ----------------
__global__ __launch_bounds__(256) void gsmall_kernel(
    const int* __restrict__ idsA, const float* __restrict__ E0A, const float* __restrict__ mulA,
    const float* __restrict__ MA, float* __restrict__ outA, ushort* __restrict__ outbA,
    const int* __restrict__ idsB, const float* __restrict__ E0B, const float* __restrict__ mulB,
    const float* __restrict__ MB, float* __restrict__ outB, ushort* __restrict__ outbB) {
  const int side = blockIdx.y;
  const int* ids = side ? idsB : idsA;
  const float* E0 = side ? E0B : E0A;
  const float* mul = side ? mulB : mulA;
  const float* M = side ? MB : MA;
  float* out = side ? outB : outA;
  ushort* outb = side ? outbB : outbA;
  __shared__ float Ms[RNK*DIM];
  int t = threadIdx.x;
  for (int i = t; i < RNK*DIM; i += 256) Ms[i] = M[i];
  __syncthreads();
  int b = blockIdx.x*4 + (t >> 6), lane = t & 63;
  int u = ids[b];
  float a = E0[(size_t)u*DIM + lane];
  #pragma unroll
  for (int r = 0; r < RNK; r++) a += mul[(size_t)u*RNK + r]*Ms[r*DIM + lane];
  out[(size_t)b*DIM + lane] = a;
  outb[(size_t)b*DIM + lane] = f2bf(a);
}

// ---------------- fp32 -> bf16 conversion fused with sum-of-squares (merged; 1 atomic/block) ----------------
__global__ __launch_bounds__(256) void convsq_kernel(const float* __restrict__ inA, ushort* __restrict__ outA,
                                                     const float* __restrict__ inB, ushort* __restrict__ outB,
                                                     int n4, float* __restrict__ acc) {
  const float* in = blockIdx.y ? inB : inA;
  ushort* out = blockIdx.y ? outB : outA;
  __shared__ float ls[4];
  int t = threadIdx.x;
  int idx = blockIdx.x*256 + t;
  int stride = gridDim.x*256;
  float s = 0.f;
  for (int i = idx; i < n4; i += stride) {
    float4 v = *(const float4*)&in[(size_t)i*4];
    ushort4 o;
    o.x = f2bf(v.x); o.y = f2bf(v.y); o.z = f2bf(v.z); o.w = f2bf(v.w);
    *(ushort4*)&out[(size_t)i*4] = o;
    s += v.x*v.x + v.y*v.y + v.z*v.z + v.w*v.w;
  }
  #pragma unroll
  for (int o = 32; o > 0; o >>= 1) s += __shfl_xor(s, o);
  if ((t & 63) == 0) ls[t >> 6] = s;
  __syncthreads();
  if (t == 0) atomicAdd(acc, ls[0] + ls[1] + ls[2] + ls[3]);
}

// ---------------- bf16 MFMA fused GEMM + exp + row-sum (merged sides; 2 b-tiles/block) ----------------
__global__ __launch_bounds__(256) void lse_mfma_kernel(
    const ushort* __restrict__ Ag, const ushort* __restrict__ Xg, float* __restrict__ seg,
    const ushort* __restrict__ Ad, const ushort* __restrict__ Xd, float* __restrict__ sed,
    int nj) {
  const ushort* A = blockIdx.y ? Ad : Ag;
  const ushort* X = blockIdx.y ? Xd : Xg;
  float* sumexp = blockIdx.y ? sed : seg;
  __shared__ __align__(16) ushort Xs[64*68];
  int t = threadIdx.x, lane = t & 63, w = t >> 6;
  int bt = blockIdx.x & 15, js = blockIdx.x >> 4;
  int b0 = bt*128;
  int m = lane & 15, q = lane >> 4;
  const ushort* Arow0 = A + (size_t)(b0 + w*16 + m)*DIM + q*8;
  const ushort* Arow1 = A + (size_t)(b0 + 64 + w*16 + m)*DIM + q*8;
  bfrag a00 = *(const bfrag*)(Arow0);
  bfrag a01 = *(const bfrag*)(Arow0 + 32);
  bfrag a10 = *(const bfrag*)(Arow1);
  bfrag a11 = *(const bfrag*)(Arow1 + 32);
  float rs[2][4] = {{0.f,0.f,0.f,0.f},{0.f,0.f,0.f,0.f}};
  int njt = (nj + 63) >> 6;
  for (int jt = js; jt < njt; jt += NSL) {
    int j0 = jt << 6;
    __syncthreads();
    for (int c = t; c < 512; c += 256) {
      int r = c >> 3, k8 = (c & 7) << 3;
      int j = j0 + r;
      ushort4 v0 = {0,0,0,0}, v1 = {0,0,0,0};
      if (j < nj) {
        const ushort4* src = (const ushort4*)(X + (size_t)j*DIM + k8);
        v0 = src[0]; v1 = src[1];
      }
      *(ushort4*)&Xs[r*68 + k8]     = v0;
      *(ushort4*)&Xs[r*68 + k8 + 4] = v1;
    }
    __syncthreads();
    #pragma unroll
    for (int jq = 0; jq < 4; jq++) {
      int jr = jq*16 + m;
      union { bfrag f; uint2 u2[2]; } B0, B1;
      B0.u2[0] = *(const uint2*)&Xs[jr*68 + q*8];
      B0.u2[1] = *(const uint2*)&Xs[jr*68 + q*8 + 4];
      B1.u2[0] = *(const uint2*)&Xs[jr*68 + 32 + q*8];
      B1.u2[1] = *(const uint2*)&Xs[jr*68 + 32 + q*8 + 4];
      f32x4 acc0 = {0.f, 0.f, 0.f, 0.f};
      f32x4 acc1 = {0.f, 0.f, 0.f, 0.f};
      acc0 = __builtin_amdgcn_mfma_f32_16x16x32_bf16(a00, B0.f, acc0, 0, 0, 0);
      acc0 = __builtin_amdgcn_mfma_f32_16x16x32_bf16(a01, B1.f, acc0, 0, 0, 0);
      acc1 = __builtin_amdgcn_mfma_f32_16x16x32_bf16(a10, B0.f, acc1, 0, 0, 0);
      acc1 = __builtin_amdgcn_mfma_f32_16x16x32_bf16(a11, B1.f, acc1, 0, 0, 0);
      int jg = j0 + jr;
      if (jg < nj) {
        rs[0][0] += __expf(acc0[0]*INVT);
        rs[0][1] += __expf(acc0[1]*INVT);
        rs[0][2] += __expf(acc0[2]*INVT);
        rs[0][3] += __expf(acc0[3]*INVT);
        rs[1][0] += __expf(acc1[0]*INVT);
        rs[1][1] += __expf(acc1[1]*INVT);
        rs[1][2] += __expf(acc1[2]*INVT);
        rs[1][3] += __expf(acc1[3]*INVT);
      }
    }
  }
  #pragma unroll
  for (int h = 0; h < 2; h++) {
    #pragma unroll
    for (int o = 1; o < 16; o <<= 1) {
      rs[h][0] += __shfl_xor(rs[h][0], o);
      rs[h][1] += __shfl_xor(rs[h][1], o);
      rs[h][2] += __shfl_xor(rs[h][2], o);
      rs[h][3] += __shfl_xor(rs[h][3], o);
    }
  }
  if (m == 0) {
    #pragma unroll
    for (int h = 0; h < 2; h++) {
      float* dst = &sumexp[b0 + h*64 + w*16 + q*4];
      atomicAdd(&dst[0], rs[h][0]);
      atomicAdd(&dst[1], rs[h][1]);
      atomicAdd(&dst[2], rs[h][2]);
      atomicAdd(&dst[3], rs[h][3]);
    }
  }
}

// ---------------- per-sample terms (bf16 E_sum tables); 3 atomics/block ----------------
__global__ __launch_bounds__(256) void perb_kernel(const int* __restrict__ uids, const int* __restrict__ iids,
    const int* __restrict__ pos, const int* __restrict__ neg,
    const float* __restrict__ Ggu, const float* __restrict__ Gdi,
    const ushort* __restrict__ Egs_b, const ushort* __restrict__ Eds_b,
    const float* __restrict__ seg, const float* __restrict__ sed,
    float* __restrict__ accs) {
  __shared__ float lsum[3][4];
  int t = threadIdx.x, lane = t & 63, w = t >> 6;
  int b = blockIdx.x*4 + w;
  int u = uids[b], it = iids[b], p = pos[b], ng = neg[b];
  float egu = bf2f(Egs_b[(size_t)u*DIM + lane]);
  float d1 = Ggu[(size_t)b*DIM + lane]*egu;
  float d2 = Gdi[(size_t)b*DIM + lane]*bf2f(Eds_b[(size_t)it*DIM + lane]);
  float d3 = egu*bf2f(Eds_b[(size_t)p*DIM + lane]);
  float d4 = egu*bf2f(Eds_b[(size_t)ng*DIM + lane]);
  #pragma unroll
  for (int o = 32; o > 0; o >>= 1) {
    d1 += __shfl_xor(d1, o);
    d2 += __shfl_xor(d2, o);
    d3 += __shfl_xor(d3, o);
    d4 += __shfl_xor(d4, o);
  }
  if (lane == 0) {
    float pterm = fminf(fmaxf(d1*INVT, -5.f), 5.f) + fminf(fmaxf(d2*INVT, -5.f), 5.f);
    float diff = d3 - d4;
    lsum[0][w] = pterm;
    lsum[1][w] = log1pf(expf(-diff));
    lsum[2][w] = logf(seg[b] + 1e-8f) + logf(sed[b] + 1e-8f);
  }
  __syncthreads();
  if (t < 3) atomicAdd(&accs[t], lsum[t][0] + lsum[t][1] + lsum[t][2] + lsum[t][3]);
}

__global__ void final_kernel(const float* __restrict__ accs, float* __restrict__ out) {
  float posm = accs[0]*(1.f/BSZ);
  float lr   = accs[1]*(1.f/BSZ);
  float negm = accs[2]*(1.f/BSZ);
  float reg  = 1e-7f*accs[3];
  float l1ls = 0.2f*(negm - posm);
  out[0] = lr + l1ls + reg;
  out[1] = lr;
  out[2] = l1ls;
}

extern "C" void kernel_launch(void* const* d_in, const int* in_sizes, int n_in,
                              void* d_out, int out_size, void* d_ws, size_t ws_size,
                              hipStream_t stream) {
  (void)in_sizes; (void)n_in; (void)out_size;
  const int*   uids = (const int*)d_in[0];
  const int*   iids = (const int*)d_in[1];
  const int*   pos  = (const int*)d_in[2];
  const int*   neg  = (const int*)d_in[3];
  const float* Eg0  = (const float*)d_in[4];
  const float* Ed0  = (const float*)d_in[5];
  const int*   rows = (const int*)d_in[6];
  const int*   cols = (const int*)d_in[7];
  const float* vals = (const float*)d_in[8];
  const float* gms  = (const float*)d_in[9];
  const float* vms  = (const float*)d_in[10];
  const float* ut   = (const float*)d_in[11];
  const float* vt   = (const float*)d_in[12];
  const float* drop = (const float*)d_in[13];
  float* out = (float*)d_out;

  float* ws = (float*)d_ws;
  const size_t ED = (size_t)N_Gc*DIM;  // 3.2M
  float* REG_A = ws;           // [ED] : stage_r -> (Zg0_b, Zd0_b)
  float* REG_B = REG_A + ED;   // [ED] : stage_c -> (Eg0_b,Ed0_b) -> (Egs_b,Eds_b)
  int* ptr_r = (int*)(REG_B + ED);
  int* ptr_c = ptr_r + (N_Gc + 1);
  int* bptr_r = ptr_c + (N_Dc + 1);
  int* bptr_c = bptr_r + (NBK3 + 1);
  int* cntR = bptr_c + (NBK3 + 1);
  int* cntC = cntR + NBK3*NBLK;
  int* cbR  = cntC + NBK3*NBLK;
  int* cbC  = cbR + NBK3*NBLK;
  u32* ew_r0 = (u32*)(cbC + NBK3*NBLK);
  u32* ew_r1 = ew_r0 + NNZc;
  u32* ew_c0 = ew_r1 + NNZc;
  u32* ew_c1 = ew_c0 + NNZc;
  float* Ggu = (float*)(ew_c1 + NNZc);
  float* Gdi = Ggu + (size_t)BSZ*DIM;
  ushort* Ggu_b = (ushort*)(Gdi + (size_t)BSZ*DIM);
  ushort* Gdi_b = Ggu_b + (size_t)BSZ*DIM;
  float* Mg  = (float*)(Gdi_b + (size_t)BSZ*DIM);
  float* Md  = Mg + RNK*DIM;
  float* seg = Md + RNK*DIM;            // zeroed zone starts here
  float* sed = seg + BSZ;
  float* accs = sed + BSZ;              // 16 floats
  float* MpG = accs + 16;               // matred partials: MBLK*2048 each
  float* MpD = MpG + (size_t)MBLK*RNK*DIM;

  // overlays (lifetimes are disjoint on the serial stream):
  u64* stage_r = (u64*)REG_A;                   // phaseA..phaseB
  u64* stage_c = (u64*)REG_B;                   // phaseA..phaseB
  ushort* Zg0_b = (ushort*)REG_A;               // l0..matred2 (after stage_r dead)
  ushort* Zd0_b = Zg0_b + ED;
  ushort* Eg0_b = (ushort*)REG_B;               // conv..l1 (after stage_c dead)
  ushort* Ed0_b = Eg0_b + ED;
  ushort* Egs_b = (ushort*)REG_B;               // l1..end (same-index overwrite of Eg0_b in l1: thread-local RAW, safe)
  ushort* Eds_b = Egs_b + ED;

  size_t need = ((char*)(MpD + (size_t)MBLK*RNK*DIM)) - ((char*)d_ws);
  if (ws_size < need) return;

  hipMemsetAsync(seg, 0, sizeof(float)*(2*BSZ + 16), stream);

  hist3_kernel<<<NBLK, 256, 0, stream>>>(rows, cols, cntR, cntC);
  cscan2_kernel<<<2, 1024, 0, stream>>>(cntR, cbR, bptr_r, cntC, cbC, bptr_c);
  phaseA2_kernel<<<NBLK, 256, 0, stream>>>(rows, cols, vals, drop, cbR, cbC, stage_r, stage_c);
  phaseB3_kernel<<<dim3(NBK3, 2), 256, 0, stream>>>(
      bptr_r, ptr_r, stage_r, ew_r0, ew_r1,
      bptr_c, ptr_c, stage_c, ew_c0, ew_c1, N_Gc);

  // bf16 copies of the layer-0 gather tables + fused L2-reg sum-of-squares
  int n4 = (int)(ED/4);
  convsq_kernel<<<dim3(1024, 2), 256, 0, stream>>>(Eg0, Eg0_b, Ed0, Ed0_b, n4, accs + 3);

  int spmm_blocks = (N_Gc + 3)/4;
  // layer 0: Zg = A0 @ Ed0 ; Zd = A0^T @ Eg0  (bf16 gathers, bf16-only outputs)
  spmm_l0_kernel<<<dim3(spmm_blocks, 2), 256, 0, stream>>>(
      ptr_r, ew_r0, Ed0_b, Zg0_b,
      ptr_c, ew_c0, Eg0_b, Zd0_b, N_Gc);
  // layer 1 fused: Egs = Eg0 + Zg0 + A1 @ Zd0 -> bf16 ; Eds likewise (all-bf16 adds)
  spmm_l1_kernel<<<dim3(spmm_blocks, 2), 256, 0, stream>>>(
      ptr_r, ew_r1, Zd0_b, Eg0_b, Zg0_b, Egs_b,
      ptr_c, ew_c1, Zg0_b, Ed0_b, Zd0_b, Eds_b, N_Gc);

  // Mg = vt @ (Ed0 + Zd0) ; Md = ut @ (Eg0 + Zg0) — two-stage, no global atomics
  matred2_kernel<<<dim3(MBLK, 2), 256, 0, stream>>>(
      vt, Ed0, Zd0_b, MpG,
      ut, Eg0, Zg0_b, MpD, N_Dc);
  mreduce_kernel<<<dim3((RNK*DIM + 255)/256, 2), 256, 0, stream>>>(MpG, Mg, MpD, Md, MBLK);

  gsmall_kernel<<<dim3(BSZ/4, 2), 256, 0, stream>>>(
      uids, Eg0, gms, Mg, Ggu, Ggu_b,
      iids, Ed0, vms, Md, Gdi, Gdi_b);

  lse_mfma_kernel<<<dim3(16*NSL, 2), 256, 0, stream>>>(Ggu_b, Egs_b, seg, Gdi_b, Eds_b, sed, N_Gc);

  perb_kernel<<<BSZ/4, 256, 0, stream>>>(uids, iids, pos, neg, Ggu, Gdi, Egs_b, Eds_b, seg, sed, accs);
  final_kernel<<<1, 1, 0, stream>>>(accs, out);
}

// Round 17
// 568.991 us; speedup vs baseline: 1.3834x; 1.0741x over previous
//
#include <hip/hip_runtime.h>
#include <hip/hip_bf16.h>
#include <math.h>

#define N_Gc 50000
#define N_Dc 50000
#define DIM 64
#define RNK 32
#define NNZc 1600000
#define BSZ 2048
#define KEEPV (1.0f/0.9f)
#define INVT 5.0f
#define NBK3 391     // (50000+127)/128 buckets of 128 rows
#define NBLK 200     // NNZ/EPB scatter blocks
#define NSL 48       // j-slices for lse grid
#define EPB 8000     // edges per block (hist3 + phaseA)
#define MCH 256      // matred i-chunk per block
#define MBLK 196     // ceil(50000/256)
#define SCAP 6144    // LDS sort capacity (records) in phaseB3

typedef __attribute__((ext_vector_type(8))) short bfrag;
typedef __attribute__((ext_vector_type(4))) float f32x4;
typedef unsigned long long u64;
typedef unsigned int u32;

__device__ inline ushort f2bf(float f) {
  union { float f; unsigned int u; } v; v.f = f;
  unsigned int r = (v.u + 0x7fffu + ((v.u >> 16) & 1u)) >> 16;
  return (ushort)r;
}
__device__ inline float bf2f(u32 u) {
  union { unsigned int i; float f; } v; v.i = u << 16;
  return v.f;
}

// ---------------- hist3: per-(bucket,block) dense counts, no global atomics ----------------
__global__ __launch_bounds__(256) void hist3_kernel(const int* __restrict__ rows, const int* __restrict__ cols,
                                                    int* __restrict__ cntR, int* __restrict__ cntC) {
  __shared__ int lh_r[NBK3];
  __shared__ int lh_c[NBK3];
  int t = threadIdx.x, blk = blockIdx.x;
  for (int j = t; j < NBK3; j += 256) { lh_r[j] = 0; lh_c[j] = 0; }
  __syncthreads();
  int e0 = blk*EPB;
  for (int i = e0 + t; i < e0 + EPB; i += 256) {
    atomicAdd(&lh_r[__builtin_nontemporal_load(&rows[i]) >> 7], 1);
    atomicAdd(&lh_c[__builtin_nontemporal_load(&cols[i]) >> 7], 1);
  }
  __syncthreads();
  for (int j = t; j < NBK3; j += 256) {
    cntR[j*NBLK + blk] = lh_r[j];
    cntC[j*NBLK + blk] = lh_c[j];
  }
}

// ---------------- cscan2: prefix over [bucket][block] counts -> per-block bases + bucket ptr ----------------
__global__ __launch_bounds__(1024) void cscan2_kernel(const int* __restrict__ cntA, int* __restrict__ cbA, int* __restrict__ bpA,
                                                      const int* __restrict__ cntB, int* __restrict__ cbB, int* __restrict__ bpB) {
  const int n = NBK3*NBLK;
  const int* cnt = blockIdx.x ? cntB : cntA;
  int* cb = blockIdx.x ? cbB : cbA;
  int* bp = blockIdx.x ? bpB : bpA;
  __shared__ int wsum[16];
  int t = threadIdx.x, lane = t & 63, w = t >> 6;
  int carry = 0;
  for (int base = 0; base < n; base += 1024) {
    int i = base + t;
    int v = (i < n) ? cnt[i] : 0;
    int x = v;
    #pragma unroll
    for (int o = 1; o < 64; o <<= 1) { int y = __shfl_up(x, o); if (lane >= o) x += y; }
    if (lane == 63) wsum[w] = x;
    __syncthreads();
    if (t < 16) {
      int s = wsum[t];
      #pragma unroll
      for (int o = 1; o < 16; o <<= 1) { int y = __shfl_up(s, o); if (t >= o) s += y; }
      wsum[t] = s;
    }
    __syncthreads();
    int wpre = (w == 0) ? 0 : wsum[w-1];
    int total = wsum[15];
    int ex = carry + wpre + (x - v);
    if (i < n) {
      cb[i] = ex;
      if (i % NBLK == 0) bp[i/NBLK] = ex;
    }
    carry += total;
    __syncthreads();
  }
  if (t == 0) bp[NBK3] = carry;
}

// ---------------- phase A: single-pass deterministic scatter (no global atomics) ----------------
// record u64: lo32 = other_id[0:15] | rel[16:23] | d0<<24 | d1<<25 ; hi32 = val bits
__global__ __launch_bounds__(256) void phaseA2_kernel(const int* __restrict__ rows, const int* __restrict__ cols,
    const float* __restrict__ vals, const float* __restrict__ drop,
    const int* __restrict__ cbR, const int* __restrict__ cbC,
    u64* __restrict__ stage_r, u64* __restrict__ stage_c) {
  __shared__ int cnt_r[NBK3], cnt_c[NBK3];
  __shared__ int base_r[NBK3], base_c[NBK3];
  int t = threadIdx.x, blk = blockIdx.x;
  for (int j = t; j < NBK3; j += 256) {
    cnt_r[j] = 0; cnt_c[j] = 0;
    base_r[j] = cbR[j*NBLK + blk];
    base_c[j] = cbC[j*NBLK + blk];
  }
  __syncthreads();
  int e0 = blk*EPB;
  for (int i = e0 + t; i < e0 + EPB; i += 256) {
    int r = __builtin_nontemporal_load(&rows[i]);
    int c = __builtin_nontemporal_load(&cols[i]);
    u64 vb = (u64)__float_as_uint(__builtin_nontemporal_load(&vals[i])) << 32;
    unsigned int dr0 = (__builtin_nontemporal_load(&drop[i]) > 0.1f) ? (1u<<24) : 0u;
    unsigned int dc0 = (__builtin_nontemporal_load(&drop[(size_t)NNZc + i]) > 0.1f) ? (1u<<24) : 0u;
    unsigned int dr1 = (__builtin_nontemporal_load(&drop[2*(size_t)NNZc + i]) > 0.1f) ? (1u<<25) : 0u;
    unsigned int dc1 = (__builtin_nontemporal_load(&drop[3*(size_t)NNZc + i]) > 0.1f) ? (1u<<25) : 0u;
    int br = r >> 7, bc = c >> 7;
    int p = base_r[br] + atomicAdd(&cnt_r[br], 1);
    stage_r[p] = vb | (unsigned int)c | ((unsigned int)(r & 127) << 16) | dr0 | dr1;
    int q = base_c[bc] + atomicAdd(&cnt_c[bc], 1);
    stage_c[q] = vb | (unsigned int)r | ((unsigned int)(c & 127) << 16) | dc0 | dc1;
  }
}

// ---------------- phase B3 (merged sides): sort into LDS, sequential writeout of packed ew ----------------
// ew: col[0:15] | bf16(weight)[16:31]
__global__ __launch_bounds__(256) void phaseB3_kernel(
    const int* __restrict__ bptrR, int* __restrict__ ptroutR, const u64* __restrict__ stageR,
    u32* __restrict__ ew0R, u32* __restrict__ ew1R,
    const int* __restrict__ bptrC, int* __restrict__ ptroutC, const u64* __restrict__ stageC,
    u32* __restrict__ ew0C, u32* __restrict__ ew1C, int n) {
  const int side = blockIdx.y;
  const int* bptr = side ? bptrC : bptrR;
  int* ptrout = side ? ptroutC : ptroutR;
  const u64* stage = side ? stageC : stageR;
  u32* ew0 = side ? ew0C : ew0R;
  u32* ew1 = side ? ew1C : ew1R;
  __shared__ u64 sorted[SCAP];
  __shared__ int cnt[128];
  __shared__ int pos[128];
  __shared__ int wtot[2];
  int t = threadIdx.x, b = blockIdx.x;
  int base_row = b*128;
  int base = bptr[b], endp = bptr[b+1];
  int total = endp - base;
  if (t < 128) cnt[t] = 0;
  __syncthreads();
  for (int k = base + t; k < endp; k += 256) {
    unsigned int lo = (unsigned int)__builtin_nontemporal_load(&stage[k]);
    atomicAdd(&cnt[(lo >> 16) & 127], 1);
  }
  __syncthreads();
  int lane = t & 63;
  if (t < 128) {
    int c = cnt[t], x = c;
    #pragma unroll
    for (int o = 1; o < 64; o <<= 1) { int y = __shfl_up(x, o); if (lane >= o) x += y; }
    if (lane == 63) wtot[t >> 6] = x;
    __syncthreads();
    int excl = (x - c) + ((t >= 64) ? wtot[0] : 0);
    pos[t] = excl;
    int rr = base_row + t;
    if (rr <= n) ptrout[rr] = base + excl;
  } else {
    __syncthreads();
  }
  __syncthreads();
  if (total <= SCAP) {
    for (int k = base + t; k < endp; k += 256) {
      u64 rec = __builtin_nontemporal_load(&stage[k]);
      int rel = ((unsigned int)rec >> 16) & 127;
      int idx = atomicAdd(&pos[rel], 1);
      sorted[idx] = rec;
    }
    __syncthreads();
    for (int idx = t; idx < total; idx += 256) {
      u64 rec = sorted[idx];
      unsigned int lo = (unsigned int)rec;
      float v = __uint_as_float((unsigned int)(rec >> 32));
      u32 col = lo & 0xffffu;
      u32 w0 = (lo & (1u<<24)) ? (u32)f2bf(v*KEEPV) : 0u;
      u32 w1 = (lo & (1u<<25)) ? (u32)f2bf(v*KEEPV) : 0u;
      int p = base + idx;
      ew0[p] = col | (w0 << 16);
      ew1[p] = col | (w1 << 16);
    }
  } else {
    for (int k = base + t; k < endp; k += 256) {
      u64 rec = stage[k];
      unsigned int lo = (unsigned int)rec;
      int rel = (lo >> 16) & 127;
      int p = base + atomicAdd(&pos[rel], 1);
      float v = __uint_as_float((unsigned int)(rec >> 32));
      u32 col = lo & 0xffffu;
      u32 w0 = (lo & (1u<<24)) ? (u32)f2bf(v*KEEPV) : 0u;
      u32 w1 = (lo & (1u<<25)) ? (u32)f2bf(v*KEEPV) : 0u;
      ew0[p] = col | (w0 << 16);
      ew1[p] = col | (w1 << 16);
    }
  }
}

// ---------------- 2-edge-per-wave gather row-dot (packed ew, u32 row access) ----------------
// lanes 0-31 (h=0) process even edges, lanes 32-63 (h=1) odd edges; each lane loads 2 dims.
__device__ __forceinline__ float2 spmm_row2(const u32* __restrict__ ew,
                                            const u32* __restrict__ EbU, int k0, int end, int h, int j) {
  float ax = 0.f, ay = 0.f;
  int npairs = (end - k0) >> 1;
  int nb = npairs >> 2;             // batches of 4 pairs = 8 edges
  u32 me[4];
  if (nb > 0) {
    #pragma unroll
    for (int p = 0; p < 4; p++) me[p] = __builtin_nontemporal_load(&ew[k0 + 2*p + h]);
    for (int b = 1; b < nb; b++) {
      int kn = k0 + b*8;
      u32 mn[4];
      #pragma unroll
      for (int p = 0; p < 4; p++) mn[p] = __builtin_nontemporal_load(&ew[kn + 2*p + h]);
      #pragma unroll
      for (int p = 0; p < 4; p++) {
        u32 v = EbU[((me[p] & 0xffffu) << 5) | (u32)j];
        float w = bf2f(me[p] >> 16);
        ax += w*bf2f(v & 0xffffu);
        ay += w*bf2f(v >> 16);
      }
      #pragma unroll
      for (int p = 0; p < 4; p++) me[p] = mn[p];
    }
    #pragma unroll
    for (int p = 0; p < 4; p++) {
      u32 v = EbU[((me[p] & 0xffffu) << 5) | (u32)j];
      float w = bf2f(me[p] >> 16);
      ax += w*bf2f(v & 0xffffu);
      ay += w*bf2f(v >> 16);
    }
  }
  for (int k = k0 + nb*8; k + 2 <= end; k += 2) {
    u32 m = __builtin_nontemporal_load(&ew[k + h]);
    u32 v = EbU[((m & 0xffffu) << 5) | (u32)j];
    float w = bf2f(m >> 16);
    ax += w*bf2f(v & 0xffffu);
    ay += w*bf2f(v >> 16);
  }
  if ((end - k0) & 1) {
    u32 m = __builtin_nontemporal_load(&ew[end - 1]);
    u32 v = EbU[((m & 0xffffu) << 5) | (u32)j];
    float w = (h == 0) ? bf2f(m >> 16) : 0.f;
    ax += w*bf2f(v & 0xffffu);
    ay += w*bf2f(v >> 16);
  }
  ax += __shfl_xor(ax, 32);
  ay += __shfl_xor(ay, 32);
  return make_float2(ax, ay);
}

// ---------------- layer-0 SpMM (merged sides): bf16 gather -> bf16 Z ----------------
__global__ __launch_bounds__(256) void spmm_l0_kernel(
    const int* __restrict__ ptrR, const u32* __restrict__ ewR, const ushort* __restrict__ EbR, ushort* __restrict__ ZbR,
    const int* __restrict__ ptrC, const u32* __restrict__ ewC, const ushort* __restrict__ EbC, ushort* __restrict__ ZbC,
    int nrows) {
  const int side = blockIdx.y;
  const int* ptr = side ? ptrC : ptrR;
  const u32* ew = side ? ewC : ewR;
  const u32* EbU = (const u32*)(side ? EbC : EbR);
  ushort* Zb = side ? ZbC : ZbR;
  int lane = threadIdx.x & 63;
  int h = lane >> 5, j = lane & 31;
  int row = blockIdx.x*4 + (threadIdx.x >> 6);
  if (row >= nrows) return;
  float2 a = spmm_row2(ew, EbU, ptr[row], ptr[row+1], h, j);
  if (h == 0) {
    u32 packed = (u32)f2bf(a.x) | ((u32)f2bf(a.y) << 16);
    ((u32*)Zb)[(u32)row*32 + (u32)j] = packed;
  }
}

// ---------------- layer-1 SpMM (merged sides) fused with E_sum -> bf16 out ----------------
__global__ __launch_bounds__(256) void spmm_l1_kernel(
    const int* __restrict__ ptrR, const u32* __restrict__ ewR, const ushort* __restrict__ ZbOR,
    const ushort* __restrict__ E0bR, const ushort* __restrict__ ZbSR, ushort* __restrict__ EoutR,
    const int* __restrict__ ptrC, const u32* __restrict__ ewC, const ushort* __restrict__ ZbOC,
    const ushort* __restrict__ E0bC, const ushort* __restrict__ ZbSC, ushort* __restrict__ EoutC,
    int nrows) {
  const int side = blockIdx.y;
  const int* ptr = side ? ptrC : ptrR;
  const u32* ew = side ? ewC : ewR;
  const u32* ZbOU = (const u32*)(side ? ZbOC : ZbOR);
  const u32* E0bU = (const u32*)(side ? E0bC : E0bR);
  const u32* ZbSU = (const u32*)(side ? ZbSC : ZbSR);
  u32* EoutU = (u32*)(side ? EoutC : EoutR);
  int lane = threadIdx.x & 63;
  int h = lane >> 5, j = lane & 31;
  int row = blockIdx.x*4 + (threadIdx.x >> 6);
  if (row >= nrows) return;
  float2 a = spmm_row2(ew, ZbOU, ptr[row], ptr[row+1], h, j);
  if (h == 0) {
    u32 o32 = (u32)row*32 + (u32)j;
    u32 e0 = E0bU[o32];
    u32 zs = ZbSU[o32];
    float x = a.x + bf2f(e0 & 0xffffu) + bf2f(zs & 0xffffu);
    float y = a.y + bf2f(e0 >> 16) + bf2f(zs >> 16);
    EoutU[o32] = (u32)f2bf(x) | ((u32)f2bf(y) << 16);
  }
}

// ---------------- matred (merged sides) stage 1: partial M = vrow @ (E0 + Zb) ----------------
__global__ __launch_bounds__(256) void matred2_kernel(
    const float* __restrict__ vrowA, const float* __restrict__ E0A, const ushort* __restrict__ ZbA, float* __restrict__ MpA,
    const float* __restrict__ vrowB, const float* __restrict__ E0B, const ushort* __restrict__ ZbB, float* __restrict__ MpB,
    int n) {
  const int side = blockIdx.y;
  const float* vrow = side ? vrowB : vrowA;
  const float* E0 = side ? E0B : E0A;
  const ushort* Zb = side ? ZbB : ZbA;
  float* Mpart = side ? MpB : MpA;
  __shared__ float vs[RNK*MCH];
  __shared__ float part[RNK*DIM];
  int t = threadIdx.x, lane = t & 63, w = t >> 6;
  int ci0 = blockIdx.x*MCH;
  int cnt = min(MCH, n - ci0);
  for (int idx = t; idx < RNK*DIM; idx += 256) part[idx] = 0.f;
  for (int idx = t; idx < RNK*MCH; idx += 256) {
    int r = idx >> 8, i = idx & (MCH-1);
    vs[idx] = (i < cnt) ? __builtin_nontemporal_load(&vrow[(size_t)r*n + ci0 + i]) : 0.f;
  }
  __syncthreads();
  float acc[RNK];
  #pragma unroll
  for (int r = 0; r < RNK; r++) acc[r] = 0.f;
  int iw0 = w*64;
  for (int ii = 0; ii < 64; ii += 4) {
    int i = iw0 + ii;
    int gi = ci0 + i;
    float x0 = 0.f, x1 = 0.f, x2 = 0.f, x3 = 0.f;
    if (i+0 < cnt) x0 = E0[(size_t)(gi+0)*DIM + lane] + bf2f(Zb[(size_t)(gi+0)*DIM + lane]);
    if (i+1 < cnt) x1 = E0[(size_t)(gi+1)*DIM + lane] + bf2f(Zb[(size_t)(gi+1)*DIM + lane]);
    if (i+2 < cnt) x2 = E0[(size_t)(gi+2)*DIM + lane] + bf2f(Zb[(size_t)(gi+2)*DIM + lane]);
    if (i+3 < cnt) x3 = E0[(size_t)(gi+3)*DIM + lane] + bf2f(Zb[(size_t)(gi+3)*DIM + lane]);
    #pragma unroll
    for (int r = 0; r < RNK; r++) {
      float4 v4 = *(const float4*)&vs[r*MCH + i];
      acc[r] += v4.x*x0 + v4.y*x1 + v4.z*x2 + v4.w*x3;
    }
  }
  #pragma unroll
  for (int r = 0; r < RNK; r++) atomicAdd(&part[r*DIM + lane], acc[r]);
  __syncthreads();
  float* dst = Mpart + (size_t)blockIdx.x*(RNK*DIM);
  for (int idx = t; idx < RNK*DIM; idx += 256) dst[idx] = part[idx];
}

// ---------------- matred stage 2 (merged): reduce partials ----------------
__global__ __launch_bounds__(256) void mreduce_kernel(const float* __restrict__ MpA, float* __restrict__ MA,
                                                      const float* __restrict__ MpB, float* __restrict__ MB, int nblk) {
  const float* Mpart = blockIdx.y ? MpB : MpA;
  float* M = blockIdx.y ? MB : MA;
  int idx = blockIdx.x*256 + threadIdx.x;
  if (idx < RNK*DIM) {
    float s = 0.f;
    for (int b = 0; b < nblk; b++) s += Mpart[(size_t)b*(RNK*DIM) + idx];
    M[idx] = s;
  }
}

// ---------------- G rows at sampled ids (merged sides; fp32 + bf16 out) ----------------
__global__ __launch_bounds__(256) void gsmall_kernel(
    const int* __restrict__ idsA, const float* __restrict__ E0A, const float* __restrict__ mulA,
    const float* __restrict__ MA, float* __restrict__ outA, ushort* __restrict__ outbA,
    const int* __restrict__ idsB, const float* __restrict__ E0B, const float* __restrict__ mulB,
    const float* __restrict__ MB, float* __restrict__ outB, ushort* __restrict__ outbB) {
  const int side = blockIdx.y;
  const int* ids = side ? idsB : idsA;
  const float* E0 = side ? E0B : E0A;
  const float* mul = side ? mulB : mulA;
  const float* M = side ? MB : MA;
  float* out = side ? outB : outA;
  ushort* outb = side ? outbB : outbA;
  __shared__ float Ms[RNK*DIM];
  int t = threadIdx.x;
  for (int i = t; i < RNK*DIM; i += 256) Ms[i] = M[i];
  __syncthreads();
  int b = blockIdx.x*4 + (t >> 6), lane = t & 63;
  int u = ids[b];
  float a = E0[(size_t)u*DIM + lane];
  #pragma unroll
  for (int r = 0; r < RNK; r++) a += mul[(size_t)u*RNK + r]*Ms[r*DIM + lane];
  out[(size_t)b*DIM + lane] = a;
  outb[(size_t)b*DIM + lane] = f2bf(a);
}

// ---------------- fp32 -> bf16 conversion fused with sum-of-squares (merged; 1 atomic/block) ----------------
__global__ __launch_bounds__(256) void convsq_kernel(const float* __restrict__ inA, ushort* __restrict__ outA,
                                                     const float* __restrict__ inB, ushort* __restrict__ outB,
                                                     int n4, float* __restrict__ acc) {
  const float* in = blockIdx.y ? inB : inA;
  ushort* out = blockIdx.y ? outB : outA;
  __shared__ float ls[4];
  int t = threadIdx.x;
  int idx = blockIdx.x*256 + t;
  int stride = gridDim.x*256;
  float s = 0.f;
  for (int i = idx; i < n4; i += stride) {
    float4 v = *(const float4*)&in[(size_t)i*4];
    ushort4 o;
    o.x = f2bf(v.x); o.y = f2bf(v.y); o.z = f2bf(v.z); o.w = f2bf(v.w);
    *(ushort4*)&out[(size_t)i*4] = o;
    s += v.x*v.x + v.y*v.y + v.z*v.z + v.w*v.w;
  }
  #pragma unroll
  for (int o = 32; o > 0; o >>= 1) s += __shfl_xor(s, o);
  if ((t & 63) == 0) ls[t >> 6] = s;
  __syncthreads();
  if (t == 0) atomicAdd(acc, ls[0] + ls[1] + ls[2] + ls[3]);
}

// ---------------- bf16 MFMA fused GEMM + exp + row-sum (merged sides; 2 b-tiles/block) ----------------
__global__ __launch_bounds__(256) void lse_mfma_kernel(
    const ushort* __restrict__ Ag, const ushort* __restrict__ Xg, float* __restrict__ seg,
    const ushort* __restrict__ Ad, const ushort* __restrict__ Xd, float* __restrict__ sed,
    int nj) {
  const ushort* A = blockIdx.y ? Ad : Ag;
  const ushort* X = blockIdx.y ? Xd : Xg;
  float* sumexp = blockIdx.y ? sed : seg;
  __shared__ __align__(16) ushort Xs[64*68];
  int t = threadIdx.x, lane = t & 63, w = t >> 6;
  int bt = blockIdx.x & 15, js = blockIdx.x >> 4;
  int b0 = bt*128;
  int m = lane & 15, q = lane >> 4;
  const ushort* Arow0 = A + (size_t)(b0 + w*16 + m)*DIM + q*8;
  const ushort* Arow1 = A + (size_t)(b0 + 64 + w*16 + m)*DIM + q*8;
  bfrag a00 = *(const bfrag*)(Arow0);
  bfrag a01 = *(const bfrag*)(Arow0 + 32);
  bfrag a10 = *(const bfrag*)(Arow1);
  bfrag a11 = *(const bfrag*)(Arow1 + 32);
  float rs[2][4] = {{0.f,0.f,0.f,0.f},{0.f,0.f,0.f,0.f}};
  int njt = (nj + 63) >> 6;
  for (int jt = js; jt < njt; jt += NSL) {
    int j0 = jt << 6;
    __syncthreads();
    for (int c = t; c < 512; c += 256) {
      int r = c >> 3, k8 = (c & 7) << 3;
      int j = j0 + r;
      ushort4 v0 = {0,0,0,0}, v1 = {0,0,0,0};
      if (j < nj) {
        const ushort4* src = (const ushort4*)(X + (size_t)j*DIM + k8);
        v0 = src[0]; v1 = src[1];
      }
      *(ushort4*)&Xs[r*68 + k8]     = v0;
      *(ushort4*)&Xs[r*68 + k8 + 4] = v1;
    }
    __syncthreads();
    #pragma unroll
    for (int jq = 0; jq < 4; jq++) {
      int jr = jq*16 + m;
      union { bfrag f; uint2 u2[2]; } B0, B1;
      B0.u2[0] = *(const uint2*)&Xs[jr*68 + q*8];
      B0.u2[1] = *(const uint2*)&Xs[jr*68 + q*8 + 4];
      B1.u2[0] = *(const uint2*)&Xs[jr*68 + 32 + q*8];
      B1.u2[1] = *(const uint2*)&Xs[jr*68 + 32 + q*8 + 4];
      f32x4 acc0 = {0.f, 0.f, 0.f, 0.f};
      f32x4 acc1 = {0.f, 0.f, 0.f, 0.f};
      acc0 = __builtin_amdgcn_mfma_f32_16x16x32_bf16(a00, B0.f, acc0, 0, 0, 0);
      acc0 = __builtin_amdgcn_mfma_f32_16x16x32_bf16(a01, B1.f, acc0, 0, 0, 0);
      acc1 = __builtin_amdgcn_mfma_f32_16x16x32_bf16(a10, B0.f, acc1, 0, 0, 0);
      acc1 = __builtin_amdgcn_mfma_f32_16x16x32_bf16(a11, B1.f, acc1, 0, 0, 0);
      int jg = j0 + jr;
      if (jg < nj) {
        rs[0][0] += __expf(acc0[0]*INVT);
        rs[0][1] += __expf(acc0[1]*INVT);
        rs[0][2] += __expf(acc0[2]*INVT);
        rs[0][3] += __expf(acc0[3]*INVT);
        rs[1][0] += __expf(acc1[0]*INVT);
        rs[1][1] += __expf(acc1[1]*INVT);
        rs[1][2] += __expf(acc1[2]*INVT);
        rs[1][3] += __expf(acc1[3]*INVT);
      }
    }
  }
  #pragma unroll
  for (int h = 0; h < 2; h++) {
    #pragma unroll
    for (int o = 1; o < 16; o <<= 1) {
      rs[h][0] += __shfl_xor(rs[h][0], o);
      rs[h][1] += __shfl_xor(rs[h][1], o);
      rs[h][2] += __shfl_xor(rs[h][2], o);
      rs[h][3] += __shfl_xor(rs[h][3], o);
    }
  }
  if (m == 0) {
    #pragma unroll
    for (int h = 0; h < 2; h++) {
      float* dst = &sumexp[b0 + h*64 + w*16 + q*4];
      atomicAdd(&dst[0], rs[h][0]);
      atomicAdd(&dst[1], rs[h][1]);
      atomicAdd(&dst[2], rs[h][2]);
      atomicAdd(&dst[3], rs[h][3]);
    }
  }
}

// ---------------- per-sample terms (bf16 E_sum tables); 3 atomics/block ----------------
__global__ __launch_bounds__(256) void perb_kernel(const int* __restrict__ uids, const int* __restrict__ iids,
    const int* __restrict__ pos, const int* __restrict__ neg,
    const float* __restrict__ Ggu, const float* __restrict__ Gdi,
    const ushort* __restrict__ Egs_b, const ushort* __restrict__ Eds_b,
    const float* __restrict__ seg, const float* __restrict__ sed,
    float* __restrict__ accs) {
  __shared__ float lsum[3][4];
  int t = threadIdx.x, lane = t & 63, w = t >> 6;
  int b = blockIdx.x*4 + w;
  int u = uids[b], it = iids[b], p = pos[b], ng = neg[b];
  float egu = bf2f(Egs_b[(size_t)u*DIM + lane]);
  float d1 = Ggu[(size_t)b*DIM + lane]*egu;
  float d2 = Gdi[(size_t)b*DIM + lane]*bf2f(Eds_b[(size_t)it*DIM + lane]);
  float d3 = egu*bf2f(Eds_b[(size_t)p*DIM + lane]);
  float d4 = egu*bf2f(Eds_b[(size_t)ng*DIM + lane]);
  #pragma unroll
  for (int o = 32; o > 0; o >>= 1) {
    d1 += __shfl_xor(d1, o);
    d2 += __shfl_xor(d2, o);
    d3 += __shfl_xor(d3, o);
    d4 += __shfl_xor(d4, o);
  }
  if (lane == 0) {
    float pterm = fminf(fmaxf(d1*INVT, -5.f), 5.f) + fminf(fmaxf(d2*INVT, -5.f), 5.f);
    float diff = d3 - d4;
    lsum[0][w] = pterm;
    lsum[1][w] = log1pf(expf(-diff));
    lsum[2][w] = logf(seg[b] + 1e-8f) + logf(sed[b] + 1e-8f);
  }
  __syncthreads();
  if (t < 3) atomicAdd(&accs[t], lsum[t][0] + lsum[t][1] + lsum[t][2] + lsum[t][3]);
}

__global__ void final_kernel(const float* __restrict__ accs, float* __restrict__ out) {
  float posm = accs[0]*(1.f/BSZ);
  float lr   = accs[1]*(1.f/BSZ);
  float negm = accs[2]*(1.f/BSZ);
  float reg  = 1e-7f*accs[3];
  float l1ls = 0.2f*(negm - posm);
  out[0] = lr + l1ls + reg;
  out[1] = lr;
  out[2] = l1ls;
}

extern "C" void kernel_launch(void* const* d_in, const int* in_sizes, int n_in,
                              void* d_out, int out_size, void* d_ws, size_t ws_size,
                              hipStream_t stream) {
  (void)in_sizes; (void)n_in; (void)out_size;
  const int*   uids = (const int*)d_in[0];
  const int*   iids = (const int*)d_in[1];
  const int*   pos  = (const int*)d_in[2];
  const int*   neg  = (const int*)d_in[3];
  const float* Eg0  = (const float*)d_in[4];
  const float* Ed0  = (const float*)d_in[5];
  const int*   rows = (const int*)d_in[6];
  const int*   cols = (const int*)d_in[7];
  const float* vals = (const float*)d_in[8];
  const float* gms  = (const float*)d_in[9];
  const float* vms  = (const float*)d_in[10];
  const float* ut   = (const float*)d_in[11];
  const float* vt   = (const float*)d_in[12];
  const float* drop = (const float*)d_in[13];
  float* out = (float*)d_out;

  float* ws = (float*)d_ws;
  const size_t ED = (size_t)N_Gc*DIM;  // 3.2M
  float* REG_A = ws;           // [ED] : stage_r -> (Zg0_b, Zd0_b)
  float* REG_B = REG_A + ED;   // [ED] : stage_c -> (Eg0_b,Ed0_b) -> (Egs_b,Eds_b)
  int* ptr_r = (int*)(REG_B + ED);
  int* ptr_c = ptr_r + (N_Gc + 1);
  int* bptr_r = ptr_c + (N_Dc + 1);
  int* bptr_c = bptr_r + (NBK3 + 1);
  int* cntR = bptr_c + (NBK3 + 1);
  int* cntC = cntR + NBK3*NBLK;
  int* cbR  = cntC + NBK3*NBLK;
  int* cbC  = cbR + NBK3*NBLK;
  u32* ew_r0 = (u32*)(cbC + NBK3*NBLK);
  u32* ew_r1 = ew_r0 + NNZc;
  u32* ew_c0 = ew_r1 + NNZc;
  u32* ew_c1 = ew_c0 + NNZc;
  float* Ggu = (float*)(ew_c1 + NNZc);
  float* Gdi = Ggu + (size_t)BSZ*DIM;
  ushort* Ggu_b = (ushort*)(Gdi + (size_t)BSZ*DIM);
  ushort* Gdi_b = Ggu_b + (size_t)BSZ*DIM;
  float* Mg  = (float*)(Gdi_b + (size_t)BSZ*DIM);
  float* Md  = Mg + RNK*DIM;
  float* seg = Md + RNK*DIM;            // zeroed zone starts here
  float* sed = seg + BSZ;
  float* accs = sed + BSZ;              // 16 floats
  float* MpG = accs + 16;               // matred partials: MBLK*2048 each
  float* MpD = MpG + (size_t)MBLK*RNK*DIM;

  // overlays (lifetimes are disjoint on the serial stream):
  u64* stage_r = (u64*)REG_A;                   // phaseA..phaseB
  u64* stage_c = (u64*)REG_B;                   // phaseA..phaseB
  ushort* Zg0_b = (ushort*)REG_A;               // l0..matred2 (after stage_r dead)
  ushort* Zd0_b = Zg0_b + ED;
  ushort* Eg0_b = (ushort*)REG_B;               // conv..l1 (after stage_c dead)
  ushort* Ed0_b = Eg0_b + ED;
  ushort* Egs_b = (ushort*)REG_B;               // l1..end (same-index overwrite of Eg0_b in l1: thread-local RAW, safe)
  ushort* Eds_b = Egs_b + ED;

  size_t need = ((char*)(MpD + (size_t)MBLK*RNK*DIM)) - ((char*)d_ws);
  if (ws_size < need) return;

  hipMemsetAsync(seg, 0, sizeof(float)*(2*BSZ + 16), stream);

  hist3_kernel<<<NBLK, 256, 0, stream>>>(rows, cols, cntR, cntC);
  cscan2_kernel<<<2, 1024, 0, stream>>>(cntR, cbR, bptr_r, cntC, cbC, bptr_c);
  phaseA2_kernel<<<NBLK, 256, 0, stream>>>(rows, cols, vals, drop, cbR, cbC, stage_r, stage_c);
  phaseB3_kernel<<<dim3(NBK3, 2), 256, 0, stream>>>(
      bptr_r, ptr_r, stage_r, ew_r0, ew_r1,
      bptr_c, ptr_c, stage_c, ew_c0, ew_c1, N_Gc);

  // bf16 copies of the layer-0 gather tables + fused L2-reg sum-of-squares
  int n4 = (int)(ED/4);
  convsq_kernel<<<dim3(1024, 2), 256, 0, stream>>>(Eg0, Eg0_b, Ed0, Ed0_b, n4, accs + 3);

  int spmm_blocks = (N_Gc + 3)/4;
  // layer 0: Zg = A0 @ Ed0 ; Zd = A0^T @ Eg0  (bf16 gathers, bf16-only outputs)
  spmm_l0_kernel<<<dim3(spmm_blocks, 2), 256, 0, stream>>>(
      ptr_r, ew_r0, Ed0_b, Zg0_b,
      ptr_c, ew_c0, Eg0_b, Zd0_b, N_Gc);
  // layer 1 fused: Egs = Eg0 + Zg0 + A1 @ Zd0 -> bf16 ; Eds likewise (all-bf16 adds)
  spmm_l1_kernel<<<dim3(spmm_blocks, 2), 256, 0, stream>>>(
      ptr_r, ew_r1, Zd0_b, Eg0_b, Zg0_b, Egs_b,
      ptr_c, ew_c1, Zg0_b, Ed0_b, Zd0_b, Eds_b, N_Gc);

  // Mg = vt @ (Ed0 + Zd0) ; Md = ut @ (Eg0 + Zg0) — two-stage, no global atomics
  matred2_kernel<<<dim3(MBLK, 2), 256, 0, stream>>>(
      vt, Ed0, Zd0_b, MpG,
      ut, Eg0, Zg0_b, MpD, N_Dc);
  mreduce_kernel<<<dim3((RNK*DIM + 255)/256, 2), 256, 0, stream>>>(MpG, Mg, MpD, Md, MBLK);

  gsmall_kernel<<<dim3(BSZ/4, 2), 256, 0, stream>>>(
      uids, Eg0, gms, Mg, Ggu, Ggu_b,
      iids, Ed0, vms, Md, Gdi, Gdi_b);

  lse_mfma_kernel<<<dim3(16*NSL, 2), 256, 0, stream>>>(Ggu_b, Egs_b, seg, Gdi_b, Eds_b, sed, N_Gc);

  perb_kernel<<<BSZ/4, 256, 0, stream>>>(uids, iids, pos, neg, Ggu, Gdi, Egs_b, Eds_b, seg, sed, accs);
  final_kernel<<<1, 1, 0, stream>>>(accs, out);
}